// Round 12
// baseline (404.654 us; speedup 1.0000x reference)
//
#include <hip/hip_runtime.h>
#include <hip/hip_bf16.h>

#define B_  4
#define L_  2048
#define D_  768
#define DI_ 1536
#define DS_ 16
#define DTR_ 48
#define ROWS_ (B_*L_)   // 8192

typedef __hip_bfloat16 bf16;
typedef __attribute__((ext_vector_type(8))) short bf16x8;
typedef __attribute__((ext_vector_type(4))) float f32x4;
typedef __attribute__((ext_vector_type(2))) float f32x2;

__device__ __forceinline__ float silu_f(float x) { return x / (1.f + __expf(-x)); }
__device__ __forceinline__ float softplus_f(float x) { return x > 15.f ? x : __logf(1.f + __expf(x)); }
__device__ __forceinline__ float b2f(bf16 v) { return __bfloat162float(v); }
__device__ __forceinline__ bf16 f2b(float v) { return __float2bfloat16(v); }
__device__ __forceinline__ float bfb(unsigned short u) {
    union { unsigned int i; float f; } w; w.i = ((unsigned int)u) << 16; return w.f;
}
__device__ __forceinline__ short f2bbits(float v) {
    bf16 t = __float2bfloat16(v);
    return *(short*)&t;
}
__device__ __forceinline__ void gload_lds16(const void* g, void* l) {
    __builtin_amdgcn_global_load_lds((const __attribute__((address_space(1))) void*)g,
                                     (__attribute__((address_space(3))) void*)l, 16, 0, 0);
}

// packed powers: pw[k] = {r^(2k+1), r^(2k+2)}, depth-4 tree, 10 instrs
__device__ __forceinline__ void pow_tree(float r, f32x2 pw[8]) {
    float r2 = r * r;
    f32x2 rr = {r2, r2};
    f32x2 r4 = rr * rr;
    f32x2 r8 = r4 * r4;
    pw[0] = (f32x2){r, r2};
    pw[1] = pw[0] * rr;
    pw[2] = pw[0] * r4;
    pw[3] = pw[1] * r4;
    pw[4] = pw[0] * r8;
    pw[5] = pw[1] * r8;
    pw[6] = pw[2] * r8;
    pw[7] = pw[3] * r8;
}

// ---------------- weight convert+transpose: W[K][N] fp32 -> Wt[N][K] bf16 ----------------
__global__ __launch_bounds__(256) void convert_wt(const float* __restrict__ W,
                                                  bf16* __restrict__ Wt,
                                                  int K, int N) {
    __shared__ float tile[32][33];
    int bx = blockIdx.x * 32;          // N
    int by = blockIdx.y * 32;          // K
    int tx = threadIdx.x & 31, ty = threadIdx.x >> 5;   // 32 x 8
#pragma unroll
    for (int i = 0; i < 32; i += 8)
        tile[ty + i][tx] = W[(size_t)(by + ty + i) * N + bx + tx];
    __syncthreads();
#pragma unroll
    for (int i = 0; i < 32; i += 8)
        Wt[(size_t)(bx + ty + i) * K + by + tx] = f2b(tile[tx][ty + i]);
}

// W_x [1536][80] fp32 -> Wxt [80][1536] bf16
__global__ __launch_bounds__(256) void convert_wxt(const float* __restrict__ W,
                                                   bf16* __restrict__ Wt) {
    int idx = blockIdx.x * 256 + threadIdx.x;   // over 80*1536
    int n = idx / DI_, k = idx % DI_;
    Wt[idx] = f2b(W[(size_t)k * 80 + n]);
}

// W_dt [48][1536] fp32 -> Wdt_t [1536][64] bf16 (K-padded with zeros)
__global__ __launch_bounds__(256) void convert_wdt(const float* __restrict__ W,
                                                   bf16* __restrict__ Wt) {
    int idx = blockIdx.x * 256 + threadIdx.x;   // over 1536*64
    int n = idx >> 6, k = idx & 63;
    Wt[idx] = f2b(k < DTR_ ? W[(size_t)k * DI_ + n] : 0.f);
}

// ---------------- LayerNorm (fp32 -> bf16) ----------------
__global__ __launch_bounds__(256) void ln_kernel(const float* __restrict__ x,
                                                 const float* __restrict__ w,
                                                 const float* __restrict__ b,
                                                 bf16* __restrict__ xn) {
    int row = blockIdx.x;
    const float* xr = x + (size_t)row * D_;
    bf16* on = xn + (size_t)row * D_;
    int t = threadIdx.x;
    float v[3];
    float s1 = 0.f, s2 = 0.f;
#pragma unroll
    for (int i = 0; i < 3; i++) { v[i] = xr[t + 256 * i]; s1 += v[i]; s2 += v[i] * v[i]; }
#pragma unroll
    for (int off = 32; off > 0; off >>= 1) { s1 += __shfl_down(s1, off); s2 += __shfl_down(s2, off); }
    __shared__ float sa[4], sb[4];
    int wid = t >> 6, lane = t & 63;
    if (lane == 0) { sa[wid] = s1; sb[wid] = s2; }
    __syncthreads();
    if (t == 0) { sa[0] = sa[0] + sa[1] + sa[2] + sa[3]; sb[0] = sb[0] + sb[1] + sb[2] + sb[3]; }
    __syncthreads();
    float mu = sa[0] * (1.f / D_);
    float var = sb[0] * (1.f / D_) - mu * mu;
    float rs = rsqrtf(var + 1e-5f);
#pragma unroll
    for (int i = 0; i < 3; i++) {
        int c = t + 256 * i;
        on[c] = f2b((v[i] - mu) * rs * w[c] + b[c]);
    }
}

// ---------------- MFMA GEMM 1 (round-9 version): xz = xn @ W_in, M=8192 N=3072 K=768 ----------------
__global__ __launch_bounds__(256) void gemm_in_mfma(const bf16* __restrict__ A,
                                                    const bf16* __restrict__ Bt,
                                                    bf16* __restrict__ u_pre,
                                                    bf16* __restrict__ z_s) {
    const int K = D_;
    constexpr int NX = (2 * DI_) / 128;           // 24
    constexpr int NWG = NX * (ROWS_ / 128);       // 1536
    __shared__ __align__(16) short As[128 * 32];
    __shared__ __align__(16) short Bs[128 * 32];
    int tid = threadIdx.x;
    int lane = tid & 63, wid = tid >> 6;
    int wr = wid >> 1, wc = wid & 1;          // 2x2 wave grid, each wave 64x64
    int bid = blockIdx.y * NX + blockIdx.x;
    bid = (bid & 7) * (NWG / 8) + (bid >> 3);   // bijective XCD swizzle
    int m0 = (bid / NX) * 128, n0 = (bid % NX) * 128;
    f32x4 acc[4][4];
#pragma unroll
    for (int i = 0; i < 4; i++)
#pragma unroll
        for (int j = 0; j < 4; j++) acc[i][j] = (f32x4){0.f, 0.f, 0.f, 0.f};

    int rl = lane & 15;
    int kb = (lane >> 4) * 8;

    for (int k0 = 0; k0 < K; k0 += 32) {
#pragma unroll
        for (int c = 0; c < 2; c++) {
            int s = c * 256 + tid;
            int r = s >> 2, sg = (s & 3) * 8;
            gload_lds16(A + (size_t)(m0 + r) * K + k0 + sg, &As[(c * 256 + wid * 64) * 8]);
            gload_lds16(Bt + (size_t)(n0 + r) * K + k0 + sg, &Bs[(c * 256 + wid * 64) * 8]);
        }
        __syncthreads();
        bf16x8 av[4], bv[4];
#pragma unroll
        for (int i = 0; i < 4; i++)
            av[i] = *(const bf16x8*)&As[(wr * 64 + i * 16 + rl) * 32 + kb];
#pragma unroll
        for (int j = 0; j < 4; j++)
            bv[j] = *(const bf16x8*)&Bs[(wc * 64 + j * 16 + rl) * 32 + kb];
#pragma unroll
        for (int i = 0; i < 4; i++)
#pragma unroll
            for (int j = 0; j < 4; j++)
                acc[i][j] = __builtin_amdgcn_mfma_f32_16x16x32_bf16(av[i], bv[j], acc[i][j], 0, 0, 0);
        __syncthreads();
    }
#pragma unroll
    for (int i = 0; i < 4; i++) {
        int mrow = m0 + wr * 64 + i * 16 + (lane >> 4) * 4;
#pragma unroll
        for (int j = 0; j < 4; j++) {
            int ncol = n0 + wc * 64 + j * 16 + rl;
#pragma unroll
            for (int r = 0; r < 4; r++) {
                float v = acc[i][j][r];
                int m = mrow + r;
                if (ncol < DI_) u_pre[(size_t)m * DI_ + ncol] = f2b(v);
                else            z_s[(size_t)m * DI_ + (ncol - DI_)] = f2b(silu_f(v));
            }
        }
    }
}

// ---------------- MFMA GEMM 2: out = x + 0.5*(g_f+g_b) @ W_out, M=8192 N=768 K=1536 ----------------
__global__ __launch_bounds__(256) void gemm_out_mfma(const bf16* __restrict__ gf,
                                                     const bf16* __restrict__ gb,
                                                     const bf16* __restrict__ Bt,   // [768][1536]
                                                     const float* __restrict__ resid,
                                                     float* __restrict__ C) {
    const int K = DI_, N = D_;
    constexpr int NX = D_ / 128;                  // 6
    constexpr int NWG = NX * (ROWS_ / 128);       // 384
    __shared__ __align__(16) short As[128 * 32];
    __shared__ __align__(16) short Bs[128 * 32];
    int tid = threadIdx.x;
    int lane = tid & 63, wid = tid >> 6;
    int wr = wid >> 1, wc = wid & 1;
    int bid = blockIdx.y * NX + blockIdx.x;
    bid = (bid & 7) * (NWG / 8) + (bid >> 3);
    int m0 = (bid / NX) * 128, n0 = (bid % NX) * 128;
    f32x4 acc[4][4];
#pragma unroll
    for (int i = 0; i < 4; i++)
#pragma unroll
        for (int j = 0; j < 4; j++) acc[i][j] = (f32x4){0.f, 0.f, 0.f, 0.f};

    int rl = lane & 15;
    int kb = (lane >> 4) * 8;

    for (int k0 = 0; k0 < K; k0 += 32) {
        // A: reg-stage sum of g_f + g_b into LDS (same linear layout)
#pragma unroll
        for (int c = 0; c < 2; c++) {
            int s = c * 256 + tid;
            int r = s >> 2, sg = (s & 3) * 8;
            size_t off = (size_t)(m0 + r) * K + k0 + sg;
            const unsigned short* pf = (const unsigned short*)(gf + off);
            const unsigned short* pb = (const unsigned short*)(gb + off);
            ushort4 a0 = *(const ushort4*)pf, a1 = *(const ushort4*)(pf + 4);
            ushort4 b0 = *(const ushort4*)pb, b1 = *(const ushort4*)(pb + 4);
            bf16x8 st;
            st[0] = f2bbits(bfb(a0.x) + bfb(b0.x));
            st[1] = f2bbits(bfb(a0.y) + bfb(b0.y));
            st[2] = f2bbits(bfb(a0.z) + bfb(b0.z));
            st[3] = f2bbits(bfb(a0.w) + bfb(b0.w));
            st[4] = f2bbits(bfb(a1.x) + bfb(b1.x));
            st[5] = f2bbits(bfb(a1.y) + bfb(b1.y));
            st[6] = f2bbits(bfb(a1.z) + bfb(b1.z));
            st[7] = f2bbits(bfb(a1.w) + bfb(b1.w));
            *(bf16x8*)&As[s * 8] = st;
            gload_lds16(Bt + (size_t)(n0 + r) * K + k0 + sg, &Bs[(c * 256 + wid * 64) * 8]);
        }
        __syncthreads();
        bf16x8 av[4], bv[4];
#pragma unroll
        for (int i = 0; i < 4; i++)
            av[i] = *(const bf16x8*)&As[(wr * 64 + i * 16 + rl) * 32 + kb];
#pragma unroll
        for (int j = 0; j < 4; j++)
            bv[j] = *(const bf16x8*)&Bs[(wc * 64 + j * 16 + rl) * 32 + kb];
#pragma unroll
        for (int i = 0; i < 4; i++)
#pragma unroll
            for (int j = 0; j < 4; j++)
                acc[i][j] = __builtin_amdgcn_mfma_f32_16x16x32_bf16(av[i], bv[j], acc[i][j], 0, 0, 0);
        __syncthreads();
    }
#pragma unroll
    for (int i = 0; i < 4; i++) {
        int mrow = m0 + wr * 64 + i * 16 + (lane >> 4) * 4;
#pragma unroll
        for (int j = 0; j < 4; j++) {
            int ncol = n0 + wc * 64 + j * 16 + rl;
#pragma unroll
            for (int r = 0; r < 4; r++) {
                size_t idx = (size_t)(mrow + r) * N + ncol;
                C[idx] = resid[idx] + 0.5f * acc[i][j][r];
            }
        }
    }
}

// ---------------- conv(4) + silu, both dirs, 8 channels/thread (bf16x8) ----------------
__global__ __launch_bounds__(256) void conv_kernel8(const bf16* __restrict__ up,
                                                    const float* __restrict__ cw,
                                                    const float* __restrict__ cb,
                                                    bf16* __restrict__ uf,
                                                    bf16* __restrict__ ub) {
    const int dpb = DI_ / 8;                       // 192 thread-groups per row
    int idx = blockIdx.x * 256 + threadIdx.x;      // over ROWS_*DI_/8
    int d8 = (idx % dpb) * 8;
    int bl = idx / dpb;
    int l = bl % L_, b = bl / L_;
    const bf16* base = up + (size_t)b * L_ * DI_ + d8;
    float um[7][8];
#pragma unroll
    for (int k = 0; k < 7; k++) {
        int ll = l - 3 + k;
        if (ll >= 0 && ll < L_) {
            bf16x8 v = *(const bf16x8*)(base + (size_t)ll * DI_);
#pragma unroll
            for (int e = 0; e < 8; e++) um[k][e] = bfb((unsigned short)v[e]);
        } else {
#pragma unroll
            for (int e = 0; e < 8; e++) um[k][e] = 0.f;
        }
    }
    bf16x8 of, ob;
#pragma unroll
    for (int e = 0; e < 8; e++) {
        float4 w = *(const float4*)(cw + (size_t)(d8 + e) * 4);
        float bias = cb[d8 + e];
        float cf  = bias + um[0][e] * w.x + um[1][e] * w.y + um[2][e] * w.z + um[3][e] * w.w;
        float cbw = bias + um[6][e] * w.x + um[5][e] * w.y + um[4][e] * w.z + um[3][e] * w.w;
        of[e] = f2bbits(silu_f(cf));
        ob[e] = f2bbits(silu_f(cbw));
    }
    size_t oidx = (size_t)bl * DI_ + d8;
    *(bf16x8*)(uf + oidx) = of;
    *(bf16x8*)(ub + oidx) = ob;
}

// ---------------- MFMA xdb: u @ W_x -> BC cols fp32 + dt_raw bf16 padded ----------------
__global__ __launch_bounds__(256) void xdb_mfma(const bf16* __restrict__ uf,
                                                const bf16* __restrict__ ub,
                                                const bf16* __restrict__ Wxt,   // [80][1536]
                                                float* __restrict__ xf,
                                                float* __restrict__ xb,
                                                bf16* __restrict__ drf,         // [ROWS][64]
                                                bf16* __restrict__ drb) {
    const bf16* u = blockIdx.y ? ub : uf;
    float* xout = blockIdx.y ? xb : xf;
    bf16* dout = blockIdx.y ? drb : drf;
    int m0 = blockIdx.x * 64;
    __shared__ __align__(16) short As[64 * 64];   // 64 rows x 128B, XOR-swizzled chunks
    int tid = threadIdx.x;
    int lane = tid & 63, wid = tid >> 6;
    int rl = lane & 15, hi = lane >> 4;
    f32x4 acc[5];
#pragma unroll
    for (int j = 0; j < 5; j++) acc[j] = (f32x4){0.f, 0.f, 0.f, 0.f};

    int r_loc = wid * 16 + rl;

    for (int k0 = 0; k0 < DI_; k0 += 64) {
#pragma unroll
        for (int t = 0; t < 2; t++) {
            int s = t * 256 + tid;
            int row = s >> 3, c = s & 7;
            int cs = c ^ (row & 7);              // pre-swizzled source chunk
            gload_lds16(u + (size_t)(m0 + row) * DI_ + k0 + cs * 8,
                        &As[(t * 256 + wid * 64) * 8]);
        }
        __syncthreads();
        bf16x8 av[2];
#pragma unroll
        for (int kc = 0; kc < 2; kc++) {
            int c = kc * 4 + hi;
            av[kc] = *(const bf16x8*)&As[r_loc * 64 + ((c ^ (r_loc & 7)) * 8)];
        }
#pragma unroll
        for (int j = 0; j < 5; j++)
#pragma unroll
            for (int kc = 0; kc < 2; kc++) {
                bf16x8 bv = *(const bf16x8*)(Wxt + (size_t)(j * 16 + rl) * DI_ + k0 + kc * 32 + hi * 8);
                acc[j] = __builtin_amdgcn_mfma_f32_16x16x32_bf16(av[kc], bv, acc[j], 0, 0, 0);
            }
        __syncthreads();
    }
#pragma unroll
    for (int j = 0; j < 5; j++) {
        int col = j * 16 + rl;
#pragma unroll
        for (int r = 0; r < 4; r++) {
            int m = m0 + wid * 16 + hi * 4 + r;
            float v = acc[j][r];
            if (col >= DTR_) xout[(size_t)m * 80 + col] = v;          // B,C cols for scan
            if (col < DTR_)      dout[(size_t)m * 64 + col] = f2b(v); // dt_raw
            else if (col < 64)   dout[(size_t)m * 64 + col] = f2b(0.f); // K-pad zeros
        }
    }
}

// ---------------- MFMA dt: softplus(dt_raw @ W_dt + b), M=8192 N=1536 K=64(pad) ----------------
__global__ __launch_bounds__(256) void gemm_dt_mfma(const bf16* __restrict__ drf,
                                                    const bf16* __restrict__ drb,
                                                    const bf16* __restrict__ Wdt_t, // [1536][64]
                                                    const float* __restrict__ bdt,
                                                    bf16* __restrict__ dtf,
                                                    bf16* __restrict__ dtb) {
    const bf16* A = blockIdx.z ? drb : drf;
    bf16* out = blockIdx.z ? dtb : dtf;
    int m0 = blockIdx.y * 64;
    int n0 = blockIdx.x * 256;
    __shared__ __align__(16) short As[64 * 64];
    int tid = threadIdx.x, lane = tid & 63, wid = tid >> 6;
    int rl = lane & 15, hi = lane >> 4;
#pragma unroll
    for (int t = 0; t < 2; t++) {
        int s = t * 256 + tid;
        int row = s >> 3, c = s & 7;
        gload_lds16(A + (size_t)(m0 + row) * 64 + (c ^ (row & 7)) * 8,
                    &As[(t * 256 + wid * 64) * 8]);
    }
    __syncthreads();
    int r_loc = wid * 16 + rl;
    bf16x8 av[2];
#pragma unroll
    for (int kc = 0; kc < 2; kc++) {
        int c = kc * 4 + hi;
        av[kc] = *(const bf16x8*)&As[r_loc * 64 + ((c ^ (r_loc & 7)) * 8)];
    }
    f32x4 acc[16];
#pragma unroll
    for (int j = 0; j < 16; j++) acc[j] = (f32x4){0.f, 0.f, 0.f, 0.f};
#pragma unroll
    for (int j = 0; j < 16; j++)
#pragma unroll
        for (int kc = 0; kc < 2; kc++) {
            bf16x8 bv = *(const bf16x8*)(Wdt_t + (size_t)(n0 + j * 16 + rl) * 64 + kc * 32 + hi * 8);
            acc[j] = __builtin_amdgcn_mfma_f32_16x16x32_bf16(av[kc], bv, acc[j], 0, 0, 0);
        }
#pragma unroll
    for (int j = 0; j < 16; j++) {
        int n = n0 + j * 16 + rl;
        float bb = bdt[n];
#pragma unroll
        for (int r = 0; r < 4; r++) {
            int m = m0 + wid * 16 + hi * 4 + r;
            out[(size_t)m * DI_ + n] = f2b(softplus_f(acc[j][r] + bb));
        }
    }
}

// ================= chunked parallel scan: 2 channels/thread (d, d+256) =================
__global__ __launch_bounds__(256) void scan_part1(const bf16* __restrict__ dtf,
                                                  const bf16* __restrict__ dtb,
                                                  const bf16* __restrict__ uff,
                                                  const bf16* __restrict__ ubb,
                                                  const float* __restrict__ xdbf,
                                                  const float* __restrict__ xdbb,
                                                  const float* __restrict__ A_log,
                                                  float* __restrict__ Pbuf,
                                                  float* __restrict__ Ebuf,
                                                  int NC, int CL) {
    int dir = blockIdx.z;
    int b = blockIdx.y / NC, c = blockIdx.y % NC;
    int d = blockIdx.x * 512 + threadIdx.x;       // channel A; channel B = d+256
    size_t cbase = (size_t)b * L_ * DI_ + d;
    const bf16* dt = (dir ? dtb : dtf) + cbase;
    const bf16* uu = (dir ? ubb : uff) + cbase;
    const float* xdb = (dir ? xdbb : xdbf) + (size_t)b * L_ * 80;

    int fast = 1;
#pragma unroll
    for (int s = 0; s < DS_; s++) {
        float aA = -__expf(A_log[d * DS_ + s]);
        float aB = -__expf(A_log[(d + 256) * DS_ + s]);
        fast = fast && (fabsf(aA + (float)(s + 1)) < 1e-4f * (s + 1))
                    && (fabsf(aB + (float)(s + 1)) < 1e-4f * (s + 1));
    }
    fast = __syncthreads_and(fast);

    int t0 = c * CL;
    int l0 = dir ? (L_ - 1 - t0) : t0;
    int sD = dir ? -DI_ : DI_;
    int s80 = dir ? -80 : 80;
    size_t base = (((size_t)(dir * B_ + b) * NC + c) * DS_) * DI_ + d;

    if (fast) {
        const bf16* pdt = dt + (size_t)l0 * DI_;
        const bf16* pu  = uu + (size_t)l0 * DI_;
        const float* pbr = xdb + (size_t)l0 * 80 + DTR_;
        f32x2 hA[8], hB[8];
#pragma unroll
        for (int k = 0; k < 8; k++) { hA[k] = (f32x2){0.f, 0.f}; hB[k] = (f32x2){0.f, 0.f}; }
        float sdtA = 0.f, sdtB = 0.f;
        for (int it = 0; it < CL; ++it) {
            float dtvA = b2f(pdt[0]), dtvB = b2f(pdt[256]);
            float uvA  = b2f(pu[0]),  uvB  = b2f(pu[256]);
            float xuA = dtvA * uvA, xuB = dtvB * uvB;
            sdtA += dtvA; sdtB += dtvB;
            float rA = __expf(-dtvA), rB = __expf(-dtvB);
            f32x2 pwA[8], pwB[8];
            pow_tree(rA, pwA); pow_tree(rB, pwB);
            float4 b0 = *(const float4*)(pbr);
            float4 b1 = *(const float4*)(pbr + 4);
            float4 b2v = *(const float4*)(pbr + 8);
            float4 b3 = *(const float4*)(pbr + 12);
            f32x2 B2[8] = {{b0.x, b0.y}, {b0.z, b0.w}, {b1.x, b1.y}, {b1.z, b1.w},
                           {b2v.x, b2v.y}, {b2v.z, b2v.w}, {b3.x, b3.y}, {b3.z, b3.w}};
            f32x2 xuA2 = {xuA, xuA}, xuB2 = {xuB, xuB};
#pragma unroll
            for (int k = 0; k < 8; k++) {
                hA[k] = hA[k] * pwA[k] + xuA2 * B2[k];
                hB[k] = hB[k] * pwB[k] + xuB2 * B2[k];
            }
            pdt += sD; pu += sD; pbr += s80;
        }
        float RcA = __expf(-sdtA), RcB = __expf(-sdtB);
        f32x2 pwPA[8], pwPB[8];
        pow_tree(RcA, pwPA); pow_tree(RcB, pwPB);
#pragma unroll
        for (int k = 0; k < 8; k++) {
            Pbuf[base + (size_t)(2 * k) * DI_]           = pwPA[k].x;
            Pbuf[base + (size_t)(2 * k + 1) * DI_]       = pwPA[k].y;
            Pbuf[base + (size_t)(2 * k) * DI_ + 256]     = pwPB[k].x;
            Pbuf[base + (size_t)(2 * k + 1) * DI_ + 256] = pwPB[k].y;
            Ebuf[base + (size_t)(2 * k) * DI_]           = hA[k].x;
            Ebuf[base + (size_t)(2 * k + 1) * DI_]       = hA[k].y;
            Ebuf[base + (size_t)(2 * k) * DI_ + 256]     = hB[k].x;
            Ebuf[base + (size_t)(2 * k + 1) * DI_ + 256] = hB[k].y;
        }
    } else {
        for (int ch = 0; ch < 2; ch++) {
            int off = ch * 256;
            float a[DS_];
#pragma unroll
            for (int s = 0; s < DS_; s++) a[s] = -__expf(A_log[(d + off) * DS_ + s]);
            float h[DS_], P[DS_];
#pragma unroll
            for (int s = 0; s < DS_; s++) { h[s] = 0.f; P[s] = 1.f; }
            const bf16* pdt = dt + (size_t)l0 * DI_ + off;
            const bf16* pu  = uu + (size_t)l0 * DI_ + off;
            const float* pbr = xdb + (size_t)l0 * 80 + DTR_;
            for (int it = 0; it < CL; ++it) {
                float dtv = b2f(*pdt);
                float uv = b2f(*pu);
                float xu = dtv * uv;
                float4 b0 = *(const float4*)(pbr);
                float4 b1 = *(const float4*)(pbr + 4);
                float4 b2v = *(const float4*)(pbr + 8);
                float4 b3 = *(const float4*)(pbr + 12);
                float Bv[16] = {b0.x, b0.y, b0.z, b0.w, b1.x, b1.y, b1.z, b1.w,
                                b2v.x, b2v.y, b2v.z, b2v.w, b3.x, b3.y, b3.z, b3.w};
#pragma unroll
                for (int s = 0; s < DS_; s++) {
                    float dA = __expf(dtv * a[s]);
                    h[s] = h[s] * dA + xu * Bv[s];
                    P[s] *= dA;
                }
                pdt += sD; pu += sD; pbr += s80;
            }
#pragma unroll
            for (int s = 0; s < DS_; s++) {
                Pbuf[base + (size_t)s * DI_ + off] = P[s];
                Ebuf[base + (size_t)s * DI_ + off] = h[s];
            }
        }
    }
}

__global__ __launch_bounds__(256) void scan_part2(const float* __restrict__ Pbuf,
                                                  float* __restrict__ Ebuf,
                                                  int NC) {
    int idx = blockIdx.x * 256 + threadIdx.x;   // over 2*B*DS*DI
    int d = idx % DI_;
    int rest = idx / DI_;
    int s = rest % DS_;
    int bb = rest / DS_;                        // dir*B + b
    size_t base = ((size_t)bb * NC * DS_ + s) * DI_ + d;
    float H = 0.f;
    for (int c = 0; c < NC; c++) {
        size_t aa = base + (size_t)c * DS_ * DI_;
        float P = Pbuf[aa], E = Ebuf[aa];
        Ebuf[aa] = H;
        H = P * H + E;
    }
}

__global__ __launch_bounds__(256) void scan_part3(const bf16* __restrict__ dtf,
                                                  const bf16* __restrict__ dtb,
                                                  const bf16* __restrict__ uff,
                                                  const bf16* __restrict__ ubb,
                                                  const float* __restrict__ xdbf,
                                                  const float* __restrict__ xdbb,
                                                  const bf16* __restrict__ z_s,
                                                  const float* __restrict__ A_log,
                                                  const float* __restrict__ Dp_,
                                                  const float* __restrict__ Ebuf,
                                                  bf16* __restrict__ gf,
                                                  bf16* __restrict__ gb,
                                                  int NC, int CL) {
    int dir = blockIdx.z;
    int b = blockIdx.y / NC, c = blockIdx.y % NC;
    int d = blockIdx.x * 512 + threadIdx.x;       // channel A; channel B = d+256
    size_t cbase = (size_t)b * L_ * DI_ + d;
    const bf16* dt = (dir ? dtb : dtf) + cbase;
    const bf16* uu = (dir ? ubb : uff) + cbase;
    const float* xdb = (dir ? xdbb : xdbf) + (size_t)b * L_ * 80;
    const bf16* zp = z_s + cbase;
    bf16* g = (dir ? gb : gf) + cbase;

    int fast = 1;
#pragma unroll
    for (int s = 0; s < DS_; s++) {
        float aA = -__expf(A_log[d * DS_ + s]);
        float aB = -__expf(A_log[(d + 256) * DS_ + s]);
        fast = fast && (fabsf(aA + (float)(s + 1)) < 1e-4f * (s + 1))
                    && (fabsf(aB + (float)(s + 1)) < 1e-4f * (s + 1));
    }
    fast = __syncthreads_and(fast);
    float DpA = Dp_[d], DpB = Dp_[d + 256];

    size_t base = (((size_t)(dir * B_ + b) * NC + c) * DS_) * DI_ + d;

    int t0 = c * CL;
    int l0 = dir ? (L_ - 1 - t0) : t0;
    int sD = dir ? -DI_ : DI_;
    int s80 = dir ? -80 : 80;

    if (fast) {
        const bf16* pdt = dt + (size_t)l0 * DI_;
        const bf16* pu  = uu + (size_t)l0 * DI_;
        const bf16* pz  = zp + (size_t)l0 * DI_;
        bf16* pg = g + (size_t)l0 * DI_;
        const float* pbr = xdb + (size_t)l0 * 80 + DTR_;
        f32x2 hA[8], hB[8];
#pragma unroll
        for (int k = 0; k < 8; k++) {
            hA[k] = (f32x2){Ebuf[base + (size_t)(2 * k) * DI_],
                            Ebuf[base + (size_t)(2 * k + 1) * DI_]};
            hB[k] = (f32x2){Ebuf[base + (size_t)(2 * k) * DI_ + 256],
                            Ebuf[base + (size_t)(2 * k + 1) * DI_ + 256]};
        }
        for (int it = 0; it < CL; ++it) {
            float dtvA = b2f(pdt[0]), dtvB = b2f(pdt[256]);
            float uvA  = b2f(pu[0]),  uvB  = b2f(pu[256]);
            float zvA  = b2f(pz[0]),  zvB  = b2f(pz[256]);
            float xuA = dtvA * uvA, xuB = dtvB * uvB;
            float rA = __expf(-dtvA), rB = __expf(-dtvB);
            f32x2 pwA[8], pwB[8];
            pow_tree(rA, pwA); pow_tree(rB, pwB);
            float4 b0 = *(const float4*)(pbr);
            float4 b1 = *(const float4*)(pbr + 4);
            float4 b2v = *(const float4*)(pbr + 8);
            float4 b3 = *(const float4*)(pbr + 12);
            float4 c0 = *(const float4*)(pbr + 16);
            float4 c1 = *(const float4*)(pbr + 20);
            float4 c2v = *(const float4*)(pbr + 24);
            float4 c3 = *(const float4*)(pbr + 28);
            f32x2 B2[8] = {{b0.x, b0.y}, {b0.z, b0.w}, {b1.x, b1.y}, {b1.z, b1.w},
                           {b2v.x, b2v.y}, {b2v.z, b2v.w}, {b3.x, b3.y}, {b3.z, b3.w}};
            f32x2 C2[8] = {{c0.x, c0.y}, {c0.z, c0.w}, {c1.x, c1.y}, {c1.z, c1.w},
                           {c2v.x, c2v.y}, {c2v.z, c2v.w}, {c3.x, c3.y}, {c3.z, c3.w}};
            f32x2 xuA2 = {xuA, xuA}, xuB2 = {xuB, xuB};
            f32x2 yA2 = {0.f, 0.f}, yB2 = {0.f, 0.f};
#pragma unroll
            for (int k = 0; k < 8; k++) {
                hA[k] = hA[k] * pwA[k] + xuA2 * B2[k];
                yA2 = yA2 + hA[k] * C2[k];
                hB[k] = hB[k] * pwB[k] + xuB2 * B2[k];
                yB2 = yB2 + hB[k] * C2[k];
            }
            float yA = yA2.x + yA2.y;
            float yB = yB2.x + yB2.y;
            pg[0]   = f2b((yA + uvA * DpA) * zvA);
            pg[256] = f2b((yB + uvB * DpB) * zvB);
            pdt += sD; pu += sD; pz += sD; pg += sD; pbr += s80;
        }
    } else {
        for (int ch = 0; ch < 2; ch++) {
            int off = ch * 256;
            float a[DS_];
#pragma unroll
            for (int s = 0; s < DS_; s++) a[s] = -__expf(A_log[(d + off) * DS_ + s]);
            float Dp = Dp_[d + off];
            float h[DS_];
#pragma unroll
            for (int s = 0; s < DS_; s++) h[s] = Ebuf[base + (size_t)s * DI_ + off];
            const bf16* pdt = dt + (size_t)l0 * DI_ + off;
            const bf16* pu  = uu + (size_t)l0 * DI_ + off;
            const bf16* pz  = zp + (size_t)l0 * DI_ + off;
            bf16* pg = g + (size_t)l0 * DI_ + off;
            const float* pbr = xdb + (size_t)l0 * 80 + DTR_;
            for (int it = 0; it < CL; ++it) {
                float dtv = b2f(*pdt);
                float uv = b2f(*pu);
                float zv = b2f(*pz);
                float xu = dtv * uv;
                float4 b0 = *(const float4*)(pbr);
                float4 b1 = *(const float4*)(pbr + 4);
                float4 b2v = *(const float4*)(pbr + 8);
                float4 b3 = *(const float4*)(pbr + 12);
                float4 c0 = *(const float4*)(pbr + 16);
                float4 c1 = *(const float4*)(pbr + 20);
                float4 c2v = *(const float4*)(pbr + 24);
                float4 c3 = *(const float4*)(pbr + 28);
                float Bv[16] = {b0.x, b0.y, b0.z, b0.w, b1.x, b1.y, b1.z, b1.w,
                                b2v.x, b2v.y, b2v.z, b2v.w, b3.x, b3.y, b3.z, b3.w};
                float Cv[16] = {c0.x, c0.y, c0.z, c0.w, c1.x, c1.y, c1.z, c1.w,
                                c2v.x, c2v.y, c2v.z, c2v.w, c3.x, c3.y, c3.z, c3.w};
                float y = 0.f;
#pragma unroll
                for (int s = 0; s < DS_; s++) {
                    float dA = __expf(dtv * a[s]);
                    h[s] = h[s] * dA + xu * Bv[s];
                    y += h[s] * Cv[s];
                }
                *pg = f2b((y + uv * Dp) * zv);
                pdt += sD; pu += sD; pz += sD; pg += sD; pbr += s80;
            }
        }
    }
}

// ---------------- legacy single-pass scan (ws fallback) ----------------
__global__ __launch_bounds__(256) void scan_kernel(const bf16* __restrict__ dtf,
                                                   const bf16* __restrict__ dtb,
                                                   const bf16* __restrict__ uff,
                                                   const bf16* __restrict__ ubb,
                                                   const float* __restrict__ xdbf,
                                                   const float* __restrict__ xdbb,
                                                   const bf16* __restrict__ z_s,
                                                   const float* __restrict__ A_log,
                                                   const float* __restrict__ Dp_,
                                                   bf16* __restrict__ gf,
                                                   bf16* __restrict__ gb) {
    int dir = blockIdx.z;
    int b = blockIdx.y;
    int d = blockIdx.x * 256 + threadIdx.x;
    size_t cbase = (size_t)b * L_ * DI_ + d;
    const bf16* dt = (dir ? dtb : dtf) + cbase;
    const bf16* uu = (dir ? ubb : uff) + cbase;
    const float* xdb = (dir ? xdbb : xdbf) + (size_t)b * L_ * 80;
    const bf16* zp = z_s + cbase;
    bf16* g = (dir ? gb : gf) + cbase;
    float a[DS_];
#pragma unroll
    for (int s = 0; s < DS_; s++) a[s] = -__expf(A_log[d * DS_ + s]);
    float Dp = Dp_[d];
    float h[DS_];
#pragma unroll
    for (int s = 0; s < DS_; s++) h[s] = 0.f;
    for (int tt = 0; tt < L_; ++tt) {
        int l = dir ? (L_ - 1 - tt) : tt;
        size_t off = (size_t)l * DI_;
        float dtv = b2f(dt[off]);
        float uv = b2f(uu[off]);
        float zv = b2f(zp[off]);
        float xu = dtv * uv;
        const float* br = xdb + (size_t)l * 80 + DTR_;
        float y = 0.f;
#pragma unroll
        for (int s = 0; s < DS_; s++) {
            float dA = __expf(dtv * a[s]);
            h[s] = h[s] * dA + xu * br[s];
            y += h[s] * br[16 + s];
        }
        g[off] = f2b((y + uv * Dp) * zv);
    }
}

extern "C" void kernel_launch(void* const* d_in, const int* in_sizes, int n_in,
                              void* d_out, int out_size, void* d_ws, size_t ws_size,
                              hipStream_t stream) {
    const float* x      = (const float*)d_in[0];
    const float* ln_w   = (const float*)d_in[1];
    const float* ln_b   = (const float*)d_in[2];
    const float* W_in   = (const float*)d_in[3];
    const float* conv_w = (const float*)d_in[4];
    const float* conv_b = (const float*)d_in[5];
    const float* W_x    = (const float*)d_in[6];
    const float* W_dt   = (const float*)d_in[7];
    const float* b_dt   = (const float*)d_in[8];
    const float* A_log  = (const float*)d_in[9];
    const float* D_par  = (const float*)d_in[10];
    const float* W_out  = (const float*)d_in[11];
    float* out = (float*)d_out;

    const size_t NBbf = (size_t)ROWS_ * DI_ * sizeof(bf16);     // 25,165,824 B
    const size_t XDB4 = (size_t)ROWS_ * 80 * sizeof(float);     //  2,621,440 B
    const size_t WT1  = (size_t)D_ * 2 * DI_ * sizeof(bf16);    //  4,718,592 B
    const size_t WT2  = (size_t)DI_ * D_ * sizeof(bf16);        //  2,359,296 B
    const size_t WXT  = (size_t)80 * DI_ * sizeof(bf16);        //    245,760 B
    const size_t WDT  = (size_t)DI_ * 64 * sizeof(bf16);        //    196,608 B
    const size_t DR   = (size_t)ROWS_ * 64 * sizeof(bf16);      //  1,048,576 B
    const size_t BASE = 7 * NBbf + 2 * XDB4 + WT1 + WT2 + WXT + WDT + 2 * DR;
    if (ws_size < BASE) return;  // diagnostic: absmax-fail instead of GPU fault

    auto pe_bytes = [&](int NC) { return (size_t)2 * B_ * NC * DS_ * DI_ * sizeof(float); };
    int NC = 0;
    if (ws_size >= BASE + 2 * pe_bytes(32)) NC = 32;
    else if (ws_size >= BASE + 2 * pe_bytes(16)) NC = 16;
    const int CL = NC ? L_ / NC : 0;

    char* p = (char*)d_ws;
    bf16* z_s   = (bf16*)p;  p += NBbf;
    bf16* u_f   = (bf16*)p;  p += NBbf;
    bf16* u_b   = (bf16*)p;  p += NBbf;
    bf16* slotA = (bf16*)p;  p += NBbf;   // u_pre [gemm_in..conv] / dt_f [gemm_dt..scan]
    bf16* dt_b  = (bf16*)p;  p += NBbf;
    char* slotB = p;         p += NBbf;   // xn bf16 [ln..gemm_in] / g_f bf16 [scan..gemm_out]
    bf16* g_b   = (bf16*)p;  p += NBbf;
    float* xdb_f = (float*)p; p += XDB4;
    float* xdb_b = (float*)p; p += XDB4;
    bf16* Wt_in  = (bf16*)p;  p += WT1;   // [3072][768]
    bf16* Wt_out = (bf16*)p;  p += WT2;   // [768][1536]
    bf16* Wxt    = (bf16*)p;  p += WXT;   // [80][1536]
    bf16* Wdt_t  = (bf16*)p;  p += WDT;   // [1536][64]
    bf16* dr_f   = (bf16*)p;  p += DR;    // [8192][64]
    bf16* dr_b   = (bf16*)p;  p += DR;
    float* Pbuf = (float*)p;  p += NC ? pe_bytes(NC) : 0;
    float* Ebuf = (float*)p;

    bf16* u_pre = slotA;
    bf16* dt_f  = slotA;
    bf16* xn    = (bf16*)slotB;
    bf16* g_f   = (bf16*)slotB;

    // 0. weight conversions (independent of LN)
    convert_wt<<<dim3((2 * DI_) / 32, D_ / 32), 256, 0, stream>>>(W_in, Wt_in, D_, 2 * DI_);
    convert_wt<<<dim3(D_ / 32, DI_ / 32), 256, 0, stream>>>(W_out, Wt_out, DI_, D_);
    convert_wxt<<<(80 * DI_) / 256, 256, 0, stream>>>(W_x, Wxt);
    convert_wdt<<<(DI_ * 64) / 256, 256, 0, stream>>>(W_dt, Wdt_t);
    // 1. layernorm -> bf16
    ln_kernel<<<ROWS_, 256, 0, stream>>>(x, ln_w, ln_b, xn);
    // 2. xz = xn @ W_in (MFMA, round-9 BK=32); u half -> bf16, z half -> silu -> bf16
    gemm_in_mfma<<<dim3((2 * DI_) / 128, ROWS_ / 128), 256, 0, stream>>>(xn, Wt_in, u_pre, z_s);
    // 3. conv + silu, both dirs (8 ch/thread)
    conv_kernel8<<<(ROWS_ * DI_ / 8) / 256, 256, 0, stream>>>(u_pre, conv_w, conv_b, u_f, u_b);
    // 4. xdb = u @ W_x (MFMA), both dirs; BC cols fp32 + dt_raw bf16 padded
    xdb_mfma<<<dim3(ROWS_ / 64, 2), 256, 0, stream>>>(u_f, u_b, Wxt, xdb_f, xdb_b, dr_f, dr_b);
    // 5. dt = softplus(dt_raw @ W_dt + b_dt) (MFMA), both dirs
    gemm_dt_mfma<<<dim3(DI_ / 256, ROWS_ / 64, 2), 256, 0, stream>>>(dr_f, dr_b, Wdt_t, b_dt, dt_f, dt_b);
    // 6. SSM scan (2 channels/thread in parts 1 and 3)
    if (NC) {
        scan_part1<<<dim3(DI_ / 512, B_ * NC, 2), 256, 0, stream>>>(
            dt_f, dt_b, u_f, u_b, xdb_f, xdb_b, A_log, Pbuf, Ebuf, NC, CL);
        scan_part2<<<(2 * B_ * DS_ * DI_) / 256, 256, 0, stream>>>(Pbuf, Ebuf, NC);
        scan_part3<<<dim3(DI_ / 512, B_ * NC, 2), 256, 0, stream>>>(
            dt_f, dt_b, u_f, u_b, xdb_f, xdb_b, z_s, A_log, D_par, Ebuf, g_f, g_b, NC, CL);
    } else {
        scan_kernel<<<dim3(DI_ / 256, B_, 2), 256, 0, stream>>>(
            dt_f, dt_b, u_f, u_b, xdb_f, xdb_b, z_s, A_log, D_par, g_f, g_b);
    }
    // 7. out = x + 0.5 * (g_f + g_b) @ W_out (MFMA, resid fused)
    gemm_out_mfma<<<dim3(D_ / 128, ROWS_ / 128), 256, 0, stream>>>(g_f, g_b, Wt_out, x, out);
}

// Round 13
// 388.365 us; speedup vs baseline: 1.0419x; 1.0419x over previous
//
#include <hip/hip_runtime.h>
#include <hip/hip_bf16.h>

#define B_  4
#define L_  2048
#define D_  768
#define DI_ 1536
#define DS_ 16
#define DTR_ 48
#define ROWS_ (B_*L_)   // 8192

typedef __hip_bfloat16 bf16;
typedef __attribute__((ext_vector_type(8))) short bf16x8;
typedef __attribute__((ext_vector_type(4))) float f32x4;
typedef __attribute__((ext_vector_type(2))) float f32x2;

__device__ __forceinline__ float silu_f(float x) { return x / (1.f + __expf(-x)); }
__device__ __forceinline__ float softplus_f(float x) { return x > 15.f ? x : __logf(1.f + __expf(x)); }
__device__ __forceinline__ float b2f(bf16 v) { return __bfloat162float(v); }
__device__ __forceinline__ bf16 f2b(float v) { return __float2bfloat16(v); }
__device__ __forceinline__ float bfb(unsigned short u) {
    union { unsigned int i; float f; } w; w.i = ((unsigned int)u) << 16; return w.f;
}
__device__ __forceinline__ short f2bbits(float v) {
    bf16 t = __float2bfloat16(v);
    return *(short*)&t;
}
__device__ __forceinline__ void gload_lds16(const void* g, void* l) {
    __builtin_amdgcn_global_load_lds((const __attribute__((address_space(1))) void*)g,
                                     (__attribute__((address_space(3))) void*)l, 16, 0, 0);
}

// packed powers: pw[k] = {r^(2k+1), r^(2k+2)}, depth-4 tree, 10 instrs
__device__ __forceinline__ void pow_tree(float r, f32x2 pw[8]) {
    float r2 = r * r;
    f32x2 rr = {r2, r2};
    f32x2 r4 = rr * rr;
    f32x2 r8 = r4 * r4;
    pw[0] = (f32x2){r, r2};
    pw[1] = pw[0] * rr;
    pw[2] = pw[0] * r4;
    pw[3] = pw[1] * r4;
    pw[4] = pw[0] * r8;
    pw[5] = pw[1] * r8;
    pw[6] = pw[2] * r8;
    pw[7] = pw[3] * r8;
}

// ---------------- weight convert+transpose: W[K][N] fp32 -> Wt[N][K] bf16 ----------------
__global__ __launch_bounds__(256) void convert_wt(const float* __restrict__ W,
                                                  bf16* __restrict__ Wt,
                                                  int K, int N) {
    __shared__ float tile[32][33];
    int bx = blockIdx.x * 32;          // N
    int by = blockIdx.y * 32;          // K
    int tx = threadIdx.x & 31, ty = threadIdx.x >> 5;   // 32 x 8
#pragma unroll
    for (int i = 0; i < 32; i += 8)
        tile[ty + i][tx] = W[(size_t)(by + ty + i) * N + bx + tx];
    __syncthreads();
#pragma unroll
    for (int i = 0; i < 32; i += 8)
        Wt[(size_t)(bx + ty + i) * K + by + tx] = f2b(tile[tx][ty + i]);
}

// W_x [1536][80] fp32 -> Wxt [80][1536] bf16
__global__ __launch_bounds__(256) void convert_wxt(const float* __restrict__ W,
                                                   bf16* __restrict__ Wt) {
    int idx = blockIdx.x * 256 + threadIdx.x;   // over 80*1536
    int n = idx / DI_, k = idx % DI_;
    Wt[idx] = f2b(W[(size_t)k * 80 + n]);
}

// W_dt [48][1536] fp32 -> Wdt_t [1536][64] bf16 (K-padded with zeros)
__global__ __launch_bounds__(256) void convert_wdt(const float* __restrict__ W,
                                                   bf16* __restrict__ Wt) {
    int idx = blockIdx.x * 256 + threadIdx.x;   // over 1536*64
    int n = idx >> 6, k = idx & 63;
    Wt[idx] = f2b(k < DTR_ ? W[(size_t)k * DI_ + n] : 0.f);
}

// ---------------- LayerNorm (fp32 -> bf16) ----------------
__global__ __launch_bounds__(256) void ln_kernel(const float* __restrict__ x,
                                                 const float* __restrict__ w,
                                                 const float* __restrict__ b,
                                                 bf16* __restrict__ xn) {
    int row = blockIdx.x;
    const float* xr = x + (size_t)row * D_;
    bf16* on = xn + (size_t)row * D_;
    int t = threadIdx.x;
    float v[3];
    float s1 = 0.f, s2 = 0.f;
#pragma unroll
    for (int i = 0; i < 3; i++) { v[i] = xr[t + 256 * i]; s1 += v[i]; s2 += v[i] * v[i]; }
#pragma unroll
    for (int off = 32; off > 0; off >>= 1) { s1 += __shfl_down(s1, off); s2 += __shfl_down(s2, off); }
    __shared__ float sa[4], sb[4];
    int wid = t >> 6, lane = t & 63;
    if (lane == 0) { sa[wid] = s1; sb[wid] = s2; }
    __syncthreads();
    if (t == 0) { sa[0] = sa[0] + sa[1] + sa[2] + sa[3]; sb[0] = sb[0] + sb[1] + sb[2] + sb[3]; }
    __syncthreads();
    float mu = sa[0] * (1.f / D_);
    float var = sb[0] * (1.f / D_) - mu * mu;
    float rs = rsqrtf(var + 1e-5f);
#pragma unroll
    for (int i = 0; i < 3; i++) {
        int c = t + 256 * i;
        on[c] = f2b((v[i] - mu) * rs * w[c] + b[c]);
    }
}

// ---------------- MFMA GEMM 1: xz = xn @ W_in, M=8192 N=3072 K=768 ----------------
// BK=32, 64B rows, chunk XOR by (row>>2)&3 -> 2-way (free) ds_read_b128, LDS 16KB
__global__ __launch_bounds__(256) void gemm_in_mfma(const bf16* __restrict__ A,
                                                    const bf16* __restrict__ Bt,
                                                    bf16* __restrict__ u_pre,
                                                    bf16* __restrict__ z_s) {
    const int K = D_;
    constexpr int NX = (2 * DI_) / 128;           // 24
    constexpr int NWG = NX * (ROWS_ / 128);       // 1536
    __shared__ __align__(16) short As[128 * 32];
    __shared__ __align__(16) short Bs[128 * 32];
    int tid = threadIdx.x;
    int lane = tid & 63, wid = tid >> 6;
    int wr = wid >> 1, wc = wid & 1;          // 2x2 wave grid, each wave 64x64
    int bid = blockIdx.y * NX + blockIdx.x;
    bid = (bid & 7) * (NWG / 8) + (bid >> 3);   // bijective XCD swizzle
    int m0 = (bid / NX) * 128, n0 = (bid % NX) * 128;
    f32x4 acc[4][4];
#pragma unroll
    for (int i = 0; i < 4; i++)
#pragma unroll
        for (int j = 0; j < 4; j++) acc[i][j] = (f32x4){0.f, 0.f, 0.f, 0.f};

    int rl = lane & 15, hi = lane >> 4;

    for (int k0 = 0; k0 < K; k0 += 32) {
#pragma unroll
        for (int c = 0; c < 2; c++) {
            int s = c * 256 + tid;
            int r = s >> 2;
            int cs = (s & 3) ^ ((r >> 2) & 3);   // pre-swizzled source chunk
            gload_lds16(A + (size_t)(m0 + r) * K + k0 + cs * 8, &As[(c * 256 + wid * 64) * 8]);
            gload_lds16(Bt + (size_t)(n0 + r) * K + k0 + cs * 8, &Bs[(c * 256 + wid * 64) * 8]);
        }
        __syncthreads();
        bf16x8 av[4], bv[4];
#pragma unroll
        for (int i = 0; i < 4; i++) {
            int ra = wr * 64 + i * 16 + rl;
            av[i] = *(const bf16x8*)&As[ra * 32 + ((hi ^ ((ra >> 2) & 3)) * 8)];
            int rb = wc * 64 + i * 16 + rl;
            bv[i] = *(const bf16x8*)&Bs[rb * 32 + ((hi ^ ((rb >> 2) & 3)) * 8)];
        }
#pragma unroll
        for (int i = 0; i < 4; i++)
#pragma unroll
            for (int j = 0; j < 4; j++)
                acc[i][j] = __builtin_amdgcn_mfma_f32_16x16x32_bf16(av[i], bv[j], acc[i][j], 0, 0, 0);
        __syncthreads();
    }
#pragma unroll
    for (int i = 0; i < 4; i++) {
        int mrow = m0 + wr * 64 + i * 16 + hi * 4;
#pragma unroll
        for (int j = 0; j < 4; j++) {
            int ncol = n0 + wc * 64 + j * 16 + rl;
#pragma unroll
            for (int r = 0; r < 4; r++) {
                float v = acc[i][j][r];
                int m = mrow + r;
                if (ncol < DI_) u_pre[(size_t)m * DI_ + ncol] = f2b(v);
                else            z_s[(size_t)m * DI_ + (ncol - DI_)] = f2b(silu_f(v));
            }
        }
    }
}

// ---------------- MFMA GEMM 2: out = x + 0.5*(g_f+g_b) @ W_out, M=8192 N=768 K=1536 ----------------
__global__ __launch_bounds__(256) void gemm_out_mfma(const bf16* __restrict__ gf,
                                                     const bf16* __restrict__ gb,
                                                     const bf16* __restrict__ Bt,   // [768][1536]
                                                     const float* __restrict__ resid,
                                                     float* __restrict__ C) {
    const int K = DI_, N = D_;
    constexpr int NX = D_ / 128;                  // 6
    constexpr int NWG = NX * (ROWS_ / 128);       // 384
    __shared__ __align__(16) short As[128 * 32];
    __shared__ __align__(16) short Bs[128 * 32];
    int tid = threadIdx.x;
    int lane = tid & 63, wid = tid >> 6;
    int wr = wid >> 1, wc = wid & 1;
    int bid = blockIdx.y * NX + blockIdx.x;
    bid = (bid & 7) * (NWG / 8) + (bid >> 3);
    int m0 = (bid / NX) * 128, n0 = (bid % NX) * 128;
    f32x4 acc[4][4];
#pragma unroll
    for (int i = 0; i < 4; i++)
#pragma unroll
        for (int j = 0; j < 4; j++) acc[i][j] = (f32x4){0.f, 0.f, 0.f, 0.f};

    int rl = lane & 15, hi = lane >> 4;

    for (int k0 = 0; k0 < K; k0 += 32) {
        // A: reg-stage sum of g_f + g_b into LDS (chunk-swizzled write)
#pragma unroll
        for (int c = 0; c < 2; c++) {
            int s = c * 256 + tid;
            int r = s >> 2;
            int cs = (s & 3) ^ ((r >> 2) & 3);
            size_t off = (size_t)(m0 + r) * K + k0 + (s & 3) * 8;
            const unsigned short* pf = (const unsigned short*)(gf + off);
            const unsigned short* pb = (const unsigned short*)(gb + off);
            ushort4 a0 = *(const ushort4*)pf, a1 = *(const ushort4*)(pf + 4);
            ushort4 b0 = *(const ushort4*)pb, b1 = *(const ushort4*)(pb + 4);
            bf16x8 st;
            st[0] = f2bbits(bfb(a0.x) + bfb(b0.x));
            st[1] = f2bbits(bfb(a0.y) + bfb(b0.y));
            st[2] = f2bbits(bfb(a0.z) + bfb(b0.z));
            st[3] = f2bbits(bfb(a0.w) + bfb(b0.w));
            st[4] = f2bbits(bfb(a1.x) + bfb(b1.x));
            st[5] = f2bbits(bfb(a1.y) + bfb(b1.y));
            st[6] = f2bbits(bfb(a1.z) + bfb(b1.z));
            st[7] = f2bbits(bfb(a1.w) + bfb(b1.w));
            *(bf16x8*)&As[(r * 4 + cs) * 8] = st;    // swizzled position
            gload_lds16(Bt + (size_t)(n0 + r) * K + k0 + cs * 8, &Bs[(c * 256 + wid * 64) * 8]);
        }
        __syncthreads();
        bf16x8 av[4], bv[4];
#pragma unroll
        for (int i = 0; i < 4; i++) {
            int ra = wr * 64 + i * 16 + rl;
            av[i] = *(const bf16x8*)&As[ra * 32 + ((hi ^ ((ra >> 2) & 3)) * 8)];
            int rb = wc * 64 + i * 16 + rl;
            bv[i] = *(const bf16x8*)&Bs[rb * 32 + ((hi ^ ((rb >> 2) & 3)) * 8)];
        }
#pragma unroll
        for (int i = 0; i < 4; i++)
#pragma unroll
            for (int j = 0; j < 4; j++)
                acc[i][j] = __builtin_amdgcn_mfma_f32_16x16x32_bf16(av[i], bv[j], acc[i][j], 0, 0, 0);
        __syncthreads();
    }
#pragma unroll
    for (int i = 0; i < 4; i++) {
        int mrow = m0 + wr * 64 + i * 16 + hi * 4;
#pragma unroll
        for (int j = 0; j < 4; j++) {
            int ncol = n0 + wc * 64 + j * 16 + rl;
#pragma unroll
            for (int r = 0; r < 4; r++) {
                size_t idx = (size_t)(mrow + r) * N + ncol;
                C[idx] = resid[idx] + 0.5f * acc[i][j][r];
            }
        }
    }
}

// ---------------- conv(4) + silu, both dirs, 8 channels/thread (bf16x8) ----------------
__global__ __launch_bounds__(256) void conv_kernel8(const bf16* __restrict__ up,
                                                    const float* __restrict__ cw,
                                                    const float* __restrict__ cb,
                                                    bf16* __restrict__ uf,
                                                    bf16* __restrict__ ub) {
    const int dpb = DI_ / 8;                       // 192 thread-groups per row
    int idx = blockIdx.x * 256 + threadIdx.x;      // over ROWS_*DI_/8
    int d8 = (idx % dpb) * 8;
    int bl = idx / dpb;
    int l = bl % L_, b = bl / L_;
    const bf16* base = up + (size_t)b * L_ * DI_ + d8;
    float um[7][8];
#pragma unroll
    for (int k = 0; k < 7; k++) {
        int ll = l - 3 + k;
        if (ll >= 0 && ll < L_) {
            bf16x8 v = *(const bf16x8*)(base + (size_t)ll * DI_);
#pragma unroll
            for (int e = 0; e < 8; e++) um[k][e] = bfb((unsigned short)v[e]);
        } else {
#pragma unroll
            for (int e = 0; e < 8; e++) um[k][e] = 0.f;
        }
    }
    bf16x8 of, ob;
#pragma unroll
    for (int e = 0; e < 8; e++) {
        float4 w = *(const float4*)(cw + (size_t)(d8 + e) * 4);
        float bias = cb[d8 + e];
        float cf  = bias + um[0][e] * w.x + um[1][e] * w.y + um[2][e] * w.z + um[3][e] * w.w;
        float cbw = bias + um[6][e] * w.x + um[5][e] * w.y + um[4][e] * w.z + um[3][e] * w.w;
        of[e] = f2bbits(silu_f(cf));
        ob[e] = f2bbits(silu_f(cbw));
    }
    size_t oidx = (size_t)bl * DI_ + d8;
    *(bf16x8*)(uf + oidx) = of;
    *(bf16x8*)(ub + oidx) = ob;
}

// ---------------- MFMA xdb: u @ W_x -> BC cols fp32 + dt_raw bf16 padded ----------------
__global__ __launch_bounds__(256) void xdb_mfma(const bf16* __restrict__ uf,
                                                const bf16* __restrict__ ub,
                                                const bf16* __restrict__ Wxt,   // [80][1536]
                                                float* __restrict__ xf,
                                                float* __restrict__ xb,
                                                bf16* __restrict__ drf,         // [ROWS][64]
                                                bf16* __restrict__ drb) {
    const bf16* u = blockIdx.y ? ub : uf;
    float* xout = blockIdx.y ? xb : xf;
    bf16* dout = blockIdx.y ? drb : drf;
    int m0 = blockIdx.x * 64;
    __shared__ __align__(16) short As[64 * 64];   // 64 rows x 128B, XOR-swizzled chunks
    int tid = threadIdx.x;
    int lane = tid & 63, wid = tid >> 6;
    int rl = lane & 15, hi = lane >> 4;
    f32x4 acc[5];
#pragma unroll
    for (int j = 0; j < 5; j++) acc[j] = (f32x4){0.f, 0.f, 0.f, 0.f};

    int r_loc = wid * 16 + rl;

    for (int k0 = 0; k0 < DI_; k0 += 64) {
#pragma unroll
        for (int t = 0; t < 2; t++) {
            int s = t * 256 + tid;
            int row = s >> 3, c = s & 7;
            int cs = c ^ (row & 7);              // pre-swizzled source chunk
            gload_lds16(u + (size_t)(m0 + row) * DI_ + k0 + cs * 8,
                        &As[(t * 256 + wid * 64) * 8]);
        }
        __syncthreads();
        bf16x8 av[2];
#pragma unroll
        for (int kc = 0; kc < 2; kc++) {
            int c = kc * 4 + hi;
            av[kc] = *(const bf16x8*)&As[r_loc * 64 + ((c ^ (r_loc & 7)) * 8)];
        }
#pragma unroll
        for (int j = 0; j < 5; j++)
#pragma unroll
            for (int kc = 0; kc < 2; kc++) {
                bf16x8 bv = *(const bf16x8*)(Wxt + (size_t)(j * 16 + rl) * DI_ + k0 + kc * 32 + hi * 8);
                acc[j] = __builtin_amdgcn_mfma_f32_16x16x32_bf16(av[kc], bv, acc[j], 0, 0, 0);
            }
        __syncthreads();
    }
#pragma unroll
    for (int j = 0; j < 5; j++) {
        int col = j * 16 + rl;
#pragma unroll
        for (int r = 0; r < 4; r++) {
            int m = m0 + wid * 16 + hi * 4 + r;
            float v = acc[j][r];
            if (col >= DTR_) xout[(size_t)m * 80 + col] = v;          // B,C cols for scan
            if (col < DTR_)      dout[(size_t)m * 64 + col] = f2b(v); // dt_raw
            else if (col < 64)   dout[(size_t)m * 64 + col] = f2b(0.f); // K-pad zeros
        }
    }
}

// ---------------- MFMA dt: softplus(dt_raw @ W_dt + b), M=8192 N=1536 K=64(pad) ----------------
__global__ __launch_bounds__(256) void gemm_dt_mfma(const bf16* __restrict__ drf,
                                                    const bf16* __restrict__ drb,
                                                    const bf16* __restrict__ Wdt_t, // [1536][64]
                                                    const float* __restrict__ bdt,
                                                    bf16* __restrict__ dtf,
                                                    bf16* __restrict__ dtb) {
    const bf16* A = blockIdx.z ? drb : drf;
    bf16* out = blockIdx.z ? dtb : dtf;
    int m0 = blockIdx.y * 64;
    int n0 = blockIdx.x * 256;
    __shared__ __align__(16) short As[64 * 64];
    int tid = threadIdx.x, lane = tid & 63, wid = tid >> 6;
    int rl = lane & 15, hi = lane >> 4;
#pragma unroll
    for (int t = 0; t < 2; t++) {
        int s = t * 256 + tid;
        int row = s >> 3, c = s & 7;
        gload_lds16(A + (size_t)(m0 + row) * 64 + (c ^ (row & 7)) * 8,
                    &As[(t * 256 + wid * 64) * 8]);
    }
    __syncthreads();
    int r_loc = wid * 16 + rl;
    bf16x8 av[2];
#pragma unroll
    for (int kc = 0; kc < 2; kc++) {
        int c = kc * 4 + hi;
        av[kc] = *(const bf16x8*)&As[r_loc * 64 + ((c ^ (r_loc & 7)) * 8)];
    }
    f32x4 acc[16];
#pragma unroll
    for (int j = 0; j < 16; j++) acc[j] = (f32x4){0.f, 0.f, 0.f, 0.f};
#pragma unroll
    for (int j = 0; j < 16; j++)
#pragma unroll
        for (int kc = 0; kc < 2; kc++) {
            bf16x8 bv = *(const bf16x8*)(Wdt_t + (size_t)(n0 + j * 16 + rl) * 64 + kc * 32 + hi * 8);
            acc[j] = __builtin_amdgcn_mfma_f32_16x16x32_bf16(av[kc], bv, acc[j], 0, 0, 0);
        }
#pragma unroll
    for (int j = 0; j < 16; j++) {
        int n = n0 + j * 16 + rl;
        float bb = bdt[n];
#pragma unroll
        for (int r = 0; r < 4; r++) {
            int m = m0 + wid * 16 + hi * 4 + r;
            out[(size_t)m * DI_ + n] = f2b(softplus_f(acc[j][r] + bb));
        }
    }
}

// ================= chunked parallel scan (round-10: packed fp32, incremental pointers) =================
__global__ __launch_bounds__(256) void scan_part1(const bf16* __restrict__ dtf,
                                                  const bf16* __restrict__ dtb,
                                                  const bf16* __restrict__ uff,
                                                  const bf16* __restrict__ ubb,
                                                  const float* __restrict__ xdbf,
                                                  const float* __restrict__ xdbb,
                                                  const float* __restrict__ A_log,
                                                  float* __restrict__ Pbuf,
                                                  float* __restrict__ Ebuf,
                                                  int NC, int CL) {
    int dir = blockIdx.z;
    int b = blockIdx.y / NC, c = blockIdx.y % NC;
    int d = blockIdx.x * 256 + threadIdx.x;
    size_t cbase = (size_t)b * L_ * DI_ + d;
    const bf16* dt = (dir ? dtb : dtf) + cbase;
    const bf16* uu = (dir ? ubb : uff) + cbase;
    const float* xdb = (dir ? xdbb : xdbf) + (size_t)b * L_ * 80;

    float a[DS_];
    int fast = 1;
#pragma unroll
    for (int s = 0; s < DS_; s++) {
        a[s] = -__expf(A_log[d * DS_ + s]);
        fast = fast && (fabsf(a[s] + (float)(s + 1)) < 1e-4f * (s + 1));
    }
    fast = __syncthreads_and(fast);

    int t0 = c * CL;
    int l0 = dir ? (L_ - 1 - t0) : t0;
    int sD = dir ? -DI_ : DI_;
    int s80 = dir ? -80 : 80;
    const bf16* pdt = dt + (size_t)l0 * DI_;
    const bf16* pu  = uu + (size_t)l0 * DI_;
    const float* pbr = xdb + (size_t)l0 * 80 + DTR_;

    size_t base = (((size_t)(dir * B_ + b) * NC + c) * DS_) * DI_ + d;

    if (fast) {
        f32x2 h2[8];
#pragma unroll
        for (int k = 0; k < 8; k++) h2[k] = (f32x2){0.f, 0.f};
        float sdt = 0.f;
        for (int it = 0; it < CL; ++it) {
            float dtv = b2f(*pdt);
            float uv  = b2f(*pu);
            float xu = dtv * uv;
            sdt += dtv;
            float r = __expf(-dtv);
            f32x2 pw[8]; pow_tree(r, pw);
            float4 b0 = *(const float4*)(pbr);
            float4 b1 = *(const float4*)(pbr + 4);
            float4 b2v = *(const float4*)(pbr + 8);
            float4 b3 = *(const float4*)(pbr + 12);
            f32x2 B2[8] = {{b0.x, b0.y}, {b0.z, b0.w}, {b1.x, b1.y}, {b1.z, b1.w},
                           {b2v.x, b2v.y}, {b2v.z, b2v.w}, {b3.x, b3.y}, {b3.z, b3.w}};
            f32x2 xu2 = {xu, xu};
#pragma unroll
            for (int k = 0; k < 8; k++) h2[k] = h2[k] * pw[k] + xu2 * B2[k];
            pdt += sD; pu += sD; pbr += s80;
        }
        float Rc = __expf(-sdt);
        f32x2 pwP[8]; pow_tree(Rc, pwP);
#pragma unroll
        for (int k = 0; k < 8; k++) {
            Pbuf[base + (size_t)(2 * k) * DI_]     = pwP[k].x;
            Pbuf[base + (size_t)(2 * k + 1) * DI_] = pwP[k].y;
            Ebuf[base + (size_t)(2 * k) * DI_]     = h2[k].x;
            Ebuf[base + (size_t)(2 * k + 1) * DI_] = h2[k].y;
        }
    } else {
        float h[DS_], P[DS_];
#pragma unroll
        for (int s = 0; s < DS_; s++) { h[s] = 0.f; P[s] = 1.f; }
        for (int it = 0; it < CL; ++it) {
            float dtv = b2f(*pdt);
            float uv = b2f(*pu);
            float xu = dtv * uv;
            float4 b0 = *(const float4*)(pbr);
            float4 b1 = *(const float4*)(pbr + 4);
            float4 b2v = *(const float4*)(pbr + 8);
            float4 b3 = *(const float4*)(pbr + 12);
            float Bv[16] = {b0.x, b0.y, b0.z, b0.w, b1.x, b1.y, b1.z, b1.w,
                            b2v.x, b2v.y, b2v.z, b2v.w, b3.x, b3.y, b3.z, b3.w};
#pragma unroll
            for (int s = 0; s < DS_; s++) {
                float dA = __expf(dtv * a[s]);
                h[s] = h[s] * dA + xu * Bv[s];
                P[s] *= dA;
            }
            pdt += sD; pu += sD; pbr += s80;
        }
#pragma unroll
        for (int s = 0; s < DS_; s++) {
            Pbuf[base + (size_t)s * DI_] = P[s];
            Ebuf[base + (size_t)s * DI_] = h[s];
        }
    }
}

__global__ __launch_bounds__(256) void scan_part2(const float* __restrict__ Pbuf,
                                                  float* __restrict__ Ebuf,
                                                  int NC) {
    int idx = blockIdx.x * 256 + threadIdx.x;   // over 2*B*DS*DI
    int d = idx % DI_;
    int rest = idx / DI_;
    int s = rest % DS_;
    int bb = rest / DS_;                        // dir*B + b
    size_t base = ((size_t)bb * NC * DS_ + s) * DI_ + d;
    float H = 0.f;
    for (int c = 0; c < NC; c++) {
        size_t aa = base + (size_t)c * DS_ * DI_;
        float P = Pbuf[aa], E = Ebuf[aa];
        Ebuf[aa] = H;
        H = P * H + E;
    }
}

__global__ __launch_bounds__(256) void scan_part3(const bf16* __restrict__ dtf,
                                                  const bf16* __restrict__ dtb,
                                                  const bf16* __restrict__ uff,
                                                  const bf16* __restrict__ ubb,
                                                  const float* __restrict__ xdbf,
                                                  const float* __restrict__ xdbb,
                                                  const bf16* __restrict__ z_s,
                                                  const float* __restrict__ A_log,
                                                  const float* __restrict__ Dp_,
                                                  const float* __restrict__ Ebuf,
                                                  bf16* __restrict__ gf,
                                                  bf16* __restrict__ gb,
                                                  int NC, int CL) {
    int dir = blockIdx.z;
    int b = blockIdx.y / NC, c = blockIdx.y % NC;
    int d = blockIdx.x * 256 + threadIdx.x;
    size_t cbase = (size_t)b * L_ * DI_ + d;
    const bf16* dt = (dir ? dtb : dtf) + cbase;
    const bf16* uu = (dir ? ubb : uff) + cbase;
    const float* xdb = (dir ? xdbb : xdbf) + (size_t)b * L_ * 80;
    const bf16* zp = z_s + cbase;
    bf16* g = (dir ? gb : gf) + cbase;

    float a[DS_];
    int fast = 1;
#pragma unroll
    for (int s = 0; s < DS_; s++) {
        a[s] = -__expf(A_log[d * DS_ + s]);
        fast = fast && (fabsf(a[s] + (float)(s + 1)) < 1e-4f * (s + 1));
    }
    fast = __syncthreads_and(fast);
    float Dp = Dp_[d];

    size_t base = (((size_t)(dir * B_ + b) * NC + c) * DS_) * DI_ + d;

    int t0 = c * CL;
    int l0 = dir ? (L_ - 1 - t0) : t0;
    int sD = dir ? -DI_ : DI_;
    int s80 = dir ? -80 : 80;
    const bf16* pdt = dt + (size_t)l0 * DI_;
    const bf16* pu  = uu + (size_t)l0 * DI_;
    const bf16* pz  = zp + (size_t)l0 * DI_;
    bf16* pg = g + (size_t)l0 * DI_;
    const float* pbr = xdb + (size_t)l0 * 80 + DTR_;

    if (fast) {
        f32x2 h2[8];
#pragma unroll
        for (int k = 0; k < 8; k++)
            h2[k] = (f32x2){Ebuf[base + (size_t)(2 * k) * DI_],
                            Ebuf[base + (size_t)(2 * k + 1) * DI_]};
        for (int it = 0; it < CL; ++it) {
            float dtv = b2f(*pdt);
            float uv  = b2f(*pu);
            float zv  = b2f(*pz);
            float xu = dtv * uv;
            float r = __expf(-dtv);
            f32x2 pw[8]; pow_tree(r, pw);
            float4 b0 = *(const float4*)(pbr);
            float4 b1 = *(const float4*)(pbr + 4);
            float4 b2v = *(const float4*)(pbr + 8);
            float4 b3 = *(const float4*)(pbr + 12);
            float4 c0 = *(const float4*)(pbr + 16);
            float4 c1 = *(const float4*)(pbr + 20);
            float4 c2v = *(const float4*)(pbr + 24);
            float4 c3 = *(const float4*)(pbr + 28);
            f32x2 B2[8] = {{b0.x, b0.y}, {b0.z, b0.w}, {b1.x, b1.y}, {b1.z, b1.w},
                           {b2v.x, b2v.y}, {b2v.z, b2v.w}, {b3.x, b3.y}, {b3.z, b3.w}};
            f32x2 C2[8] = {{c0.x, c0.y}, {c0.z, c0.w}, {c1.x, c1.y}, {c1.z, c1.w},
                           {c2v.x, c2v.y}, {c2v.z, c2v.w}, {c3.x, c3.y}, {c3.z, c3.w}};
            f32x2 xu2 = {xu, xu};
            f32x2 y2 = {0.f, 0.f};
#pragma unroll
            for (int k = 0; k < 8; k++) {
                h2[k] = h2[k] * pw[k] + xu2 * B2[k];
                y2 = y2 + h2[k] * C2[k];
            }
            float y = y2.x + y2.y;
            *pg = f2b((y + uv * Dp) * zv);
            pdt += sD; pu += sD; pz += sD; pg += sD; pbr += s80;
        }
    } else {
        float h[DS_];
#pragma unroll
        for (int s = 0; s < DS_; s++) h[s] = Ebuf[base + (size_t)s * DI_];
        for (int it = 0; it < CL; ++it) {
            float dtv = b2f(*pdt);
            float uv = b2f(*pu);
            float zv = b2f(*pz);
            float xu = dtv * uv;
            float4 b0 = *(const float4*)(pbr);
            float4 b1 = *(const float4*)(pbr + 4);
            float4 b2v = *(const float4*)(pbr + 8);
            float4 b3 = *(const float4*)(pbr + 12);
            float4 c0 = *(const float4*)(pbr + 16);
            float4 c1 = *(const float4*)(pbr + 20);
            float4 c2v = *(const float4*)(pbr + 24);
            float4 c3 = *(const float4*)(pbr + 28);
            float Bv[16] = {b0.x, b0.y, b0.z, b0.w, b1.x, b1.y, b1.z, b1.w,
                            b2v.x, b2v.y, b2v.z, b2v.w, b3.x, b3.y, b3.z, b3.w};
            float Cv[16] = {c0.x, c0.y, c0.z, c0.w, c1.x, c1.y, c1.z, c1.w,
                            c2v.x, c2v.y, c2v.z, c2v.w, c3.x, c3.y, c3.z, c3.w};
            float y = 0.f;
#pragma unroll
            for (int s = 0; s < DS_; s++) {
                float dA = __expf(dtv * a[s]);
                h[s] = h[s] * dA + xu * Bv[s];
                y += h[s] * Cv[s];
            }
            *pg = f2b((y + uv * Dp) * zv);
            pdt += sD; pu += sD; pz += sD; pg += sD; pbr += s80;
        }
    }
}

// ---------------- legacy single-pass scan (ws fallback) ----------------
__global__ __launch_bounds__(256) void scan_kernel(const bf16* __restrict__ dtf,
                                                   const bf16* __restrict__ dtb,
                                                   const bf16* __restrict__ uff,
                                                   const bf16* __restrict__ ubb,
                                                   const float* __restrict__ xdbf,
                                                   const float* __restrict__ xdbb,
                                                   const bf16* __restrict__ z_s,
                                                   const float* __restrict__ A_log,
                                                   const float* __restrict__ Dp_,
                                                   bf16* __restrict__ gf,
                                                   bf16* __restrict__ gb) {
    int dir = blockIdx.z;
    int b = blockIdx.y;
    int d = blockIdx.x * 256 + threadIdx.x;
    size_t cbase = (size_t)b * L_ * DI_ + d;
    const bf16* dt = (dir ? dtb : dtf) + cbase;
    const bf16* uu = (dir ? ubb : uff) + cbase;
    const float* xdb = (dir ? xdbb : xdbf) + (size_t)b * L_ * 80;
    const bf16* zp = z_s + cbase;
    bf16* g = (dir ? gb : gf) + cbase;
    float a[DS_];
#pragma unroll
    for (int s = 0; s < DS_; s++) a[s] = -__expf(A_log[d * DS_ + s]);
    float Dp = Dp_[d];
    float h[DS_];
#pragma unroll
    for (int s = 0; s < DS_; s++) h[s] = 0.f;
    for (int tt = 0; tt < L_; ++tt) {
        int l = dir ? (L_ - 1 - tt) : tt;
        size_t off = (size_t)l * DI_;
        float dtv = b2f(dt[off]);
        float uv = b2f(uu[off]);
        float zv = b2f(zp[off]);
        float xu = dtv * uv;
        const float* br = xdb + (size_t)l * 80 + DTR_;
        float y = 0.f;
#pragma unroll
        for (int s = 0; s < DS_; s++) {
            float dA = __expf(dtv * a[s]);
            h[s] = h[s] * dA + xu * br[s];
            y += h[s] * br[16 + s];
        }
        g[off] = f2b((y + uv * Dp) * zv);
    }
}

extern "C" void kernel_launch(void* const* d_in, const int* in_sizes, int n_in,
                              void* d_out, int out_size, void* d_ws, size_t ws_size,
                              hipStream_t stream) {
    const float* x      = (const float*)d_in[0];
    const float* ln_w   = (const float*)d_in[1];
    const float* ln_b   = (const float*)d_in[2];
    const float* W_in   = (const float*)d_in[3];
    const float* conv_w = (const float*)d_in[4];
    const float* conv_b = (const float*)d_in[5];
    const float* W_x    = (const float*)d_in[6];
    const float* W_dt   = (const float*)d_in[7];
    const float* b_dt   = (const float*)d_in[8];
    const float* A_log  = (const float*)d_in[9];
    const float* D_par  = (const float*)d_in[10];
    const float* W_out  = (const float*)d_in[11];
    float* out = (float*)d_out;

    const size_t NBbf = (size_t)ROWS_ * DI_ * sizeof(bf16);     // 25,165,824 B
    const size_t XDB4 = (size_t)ROWS_ * 80 * sizeof(float);     //  2,621,440 B
    const size_t WT1  = (size_t)D_ * 2 * DI_ * sizeof(bf16);    //  4,718,592 B
    const size_t WT2  = (size_t)DI_ * D_ * sizeof(bf16);        //  2,359,296 B
    const size_t WXT  = (size_t)80 * DI_ * sizeof(bf16);        //    245,760 B
    const size_t WDT  = (size_t)DI_ * 64 * sizeof(bf16);        //    196,608 B
    const size_t DR   = (size_t)ROWS_ * 64 * sizeof(bf16);      //  1,048,576 B
    const size_t BASE = 7 * NBbf + 2 * XDB4 + WT1 + WT2 + WXT + WDT + 2 * DR;
    if (ws_size < BASE) return;  // diagnostic: absmax-fail instead of GPU fault

    auto pe_bytes = [&](int NC) { return (size_t)2 * B_ * NC * DS_ * DI_ * sizeof(float); };
    int NC = 0;
    if (ws_size >= BASE + 2 * pe_bytes(32)) NC = 32;
    else if (ws_size >= BASE + 2 * pe_bytes(16)) NC = 16;
    const int CL = NC ? L_ / NC : 0;

    char* p = (char*)d_ws;
    bf16* z_s   = (bf16*)p;  p += NBbf;
    bf16* u_f   = (bf16*)p;  p += NBbf;
    bf16* u_b   = (bf16*)p;  p += NBbf;
    bf16* slotA = (bf16*)p;  p += NBbf;   // u_pre [gemm_in..conv] / dt_f [gemm_dt..scan]
    bf16* dt_b  = (bf16*)p;  p += NBbf;
    char* slotB = p;         p += NBbf;   // xn bf16 [ln..gemm_in] / g_f bf16 [scan..gemm_out]
    bf16* g_b   = (bf16*)p;  p += NBbf;
    float* xdb_f = (float*)p; p += XDB4;
    float* xdb_b = (float*)p; p += XDB4;
    bf16* Wt_in  = (bf16*)p;  p += WT1;   // [3072][768]
    bf16* Wt_out = (bf16*)p;  p += WT2;   // [768][1536]
    bf16* Wxt    = (bf16*)p;  p += WXT;   // [80][1536]
    bf16* Wdt_t  = (bf16*)p;  p += WDT;   // [1536][64]
    bf16* dr_f   = (bf16*)p;  p += DR;    // [8192][64]
    bf16* dr_b   = (bf16*)p;  p += DR;
    float* Pbuf = (float*)p;  p += NC ? pe_bytes(NC) : 0;
    float* Ebuf = (float*)p;

    bf16* u_pre = slotA;
    bf16* dt_f  = slotA;
    bf16* xn    = (bf16*)slotB;
    bf16* g_f   = (bf16*)slotB;

    // 0. weight conversions (independent of LN)
    convert_wt<<<dim3((2 * DI_) / 32, D_ / 32), 256, 0, stream>>>(W_in, Wt_in, D_, 2 * DI_);
    convert_wt<<<dim3(D_ / 32, DI_ / 32), 256, 0, stream>>>(W_out, Wt_out, DI_, D_);
    convert_wxt<<<(80 * DI_) / 256, 256, 0, stream>>>(W_x, Wxt);
    convert_wdt<<<(DI_ * 64) / 256, 256, 0, stream>>>(W_dt, Wdt_t);
    // 1. layernorm -> bf16
    ln_kernel<<<ROWS_, 256, 0, stream>>>(x, ln_w, ln_b, xn);
    // 2. xz = xn @ W_in (MFMA, BK=32 + chunk swizzle); u half -> bf16, z half -> silu -> bf16
    gemm_in_mfma<<<dim3((2 * DI_) / 128, ROWS_ / 128), 256, 0, stream>>>(xn, Wt_in, u_pre, z_s);
    // 3. conv + silu, both dirs (8 ch/thread)
    conv_kernel8<<<(ROWS_ * DI_ / 8) / 256, 256, 0, stream>>>(u_pre, conv_w, conv_b, u_f, u_b);
    // 4. xdb = u @ W_x (MFMA), both dirs; BC cols fp32 + dt_raw bf16 padded
    xdb_mfma<<<dim3(ROWS_ / 64, 2), 256, 0, stream>>>(u_f, u_b, Wxt, xdb_f, xdb_b, dr_f, dr_b);
    // 5. dt = softplus(dt_raw @ W_dt + b_dt) (MFMA), both dirs
    gemm_dt_mfma<<<dim3(DI_ / 256, ROWS_ / 64, 2), 256, 0, stream>>>(dr_f, dr_b, Wdt_t, b_dt, dt_f, dt_b);
    // 6. SSM scan (round-10 1-ch/thread)
    if (NC) {
        scan_part1<<<dim3(DI_ / 256, B_ * NC, 2), 256, 0, stream>>>(
            dt_f, dt_b, u_f, u_b, xdb_f, xdb_b, A_log, Pbuf, Ebuf, NC, CL);
        scan_part2<<<(2 * B_ * DS_ * DI_) / 256, 256, 0, stream>>>(Pbuf, Ebuf, NC);
        scan_part3<<<dim3(DI_ / 256, B_ * NC, 2), 256, 0, stream>>>(
            dt_f, dt_b, u_f, u_b, xdb_f, xdb_b, z_s, A_log, D_par, Ebuf, g_f, g_b, NC, CL);
    } else {
        scan_kernel<<<dim3(DI_ / 256, B_, 2), 256, 0, stream>>>(
            dt_f, dt_b, u_f, u_b, xdb_f, xdb_b, z_s, A_log, D_par, g_f, g_b);
    }
    // 7. out = x + 0.5 * (g_f + g_b) @ W_out (MFMA, resid fused + chunk swizzle)
    gemm_out_mfma<<<dim3(D_ / 128, ROWS_ / 128), 256, 0, stream>>>(g_f, g_b, Wt_out, x, out);
}

// Round 14
// 380.397 us; speedup vs baseline: 1.0638x; 1.0209x over previous
//
#include <hip/hip_runtime.h>
#include <hip/hip_bf16.h>

#define B_  4
#define L_  2048
#define D_  768
#define DI_ 1536
#define DS_ 16
#define DTR_ 48
#define ROWS_ (B_*L_)   // 8192

typedef __hip_bfloat16 bf16;
typedef __attribute__((ext_vector_type(8))) short bf16x8;
typedef __attribute__((ext_vector_type(4))) float f32x4;
typedef __attribute__((ext_vector_type(2))) float f32x2;

__device__ __forceinline__ float silu_f(float x) { return x / (1.f + __expf(-x)); }
__device__ __forceinline__ float softplus_f(float x) { return x > 15.f ? x : __logf(1.f + __expf(x)); }
__device__ __forceinline__ float b2f(bf16 v) { return __bfloat162float(v); }
__device__ __forceinline__ bf16 f2b(float v) { return __float2bfloat16(v); }
__device__ __forceinline__ float bfb(unsigned short u) {
    union { unsigned int i; float f; } w; w.i = ((unsigned int)u) << 16; return w.f;
}
__device__ __forceinline__ short f2bbits(float v) {
    bf16 t = __float2bfloat16(v);
    return *(short*)&t;
}
__device__ __forceinline__ void gload_lds16(const void* g, void* l) {
    __builtin_amdgcn_global_load_lds((const __attribute__((address_space(1))) void*)g,
                                     (__attribute__((address_space(3))) void*)l, 16, 0, 0);
}

// packed powers: pw[k] = {r^(2k+1), r^(2k+2)}, depth-4 tree, 10 instrs
__device__ __forceinline__ void pow_tree(float r, f32x2 pw[8]) {
    float r2 = r * r;
    f32x2 rr = {r2, r2};
    f32x2 r4 = rr * rr;
    f32x2 r8 = r4 * r4;
    pw[0] = (f32x2){r, r2};
    pw[1] = pw[0] * rr;
    pw[2] = pw[0] * r4;
    pw[3] = pw[1] * r4;
    pw[4] = pw[0] * r8;
    pw[5] = pw[1] * r8;
    pw[6] = pw[2] * r8;
    pw[7] = pw[3] * r8;
}

// ---------------- weight convert+transpose: W[K][N] fp32 -> Wt[N][K] bf16 ----------------
__global__ __launch_bounds__(256) void convert_wt(const float* __restrict__ W,
                                                  bf16* __restrict__ Wt,
                                                  int K, int N) {
    __shared__ float tile[32][33];
    int bx = blockIdx.x * 32;          // N
    int by = blockIdx.y * 32;          // K
    int tx = threadIdx.x & 31, ty = threadIdx.x >> 5;   // 32 x 8
#pragma unroll
    for (int i = 0; i < 32; i += 8)
        tile[ty + i][tx] = W[(size_t)(by + ty + i) * N + bx + tx];
    __syncthreads();
#pragma unroll
    for (int i = 0; i < 32; i += 8)
        Wt[(size_t)(bx + ty + i) * K + by + tx] = f2b(tile[tx][ty + i]);
}

// W_x [1536][80] fp32 -> Wxt [80][1536] bf16
__global__ __launch_bounds__(256) void convert_wxt(const float* __restrict__ W,
                                                   bf16* __restrict__ Wt) {
    int idx = blockIdx.x * 256 + threadIdx.x;   // over 80*1536
    int n = idx / DI_, k = idx % DI_;
    Wt[idx] = f2b(W[(size_t)k * 80 + n]);
}

// W_dt [48][1536] fp32 -> Wdt_t [1536][64] bf16 (K-padded with zeros)
__global__ __launch_bounds__(256) void convert_wdt(const float* __restrict__ W,
                                                   bf16* __restrict__ Wt) {
    int idx = blockIdx.x * 256 + threadIdx.x;   // over 1536*64
    int n = idx >> 6, k = idx & 63;
    Wt[idx] = f2b(k < DTR_ ? W[(size_t)k * DI_ + n] : 0.f);
}

// ---------------- LayerNorm (fp32 -> bf16) ----------------
__global__ __launch_bounds__(256) void ln_kernel(const float* __restrict__ x,
                                                 const float* __restrict__ w,
                                                 const float* __restrict__ b,
                                                 bf16* __restrict__ xn) {
    int row = blockIdx.x;
    const float* xr = x + (size_t)row * D_;
    bf16* on = xn + (size_t)row * D_;
    int t = threadIdx.x;
    float v[3];
    float s1 = 0.f, s2 = 0.f;
#pragma unroll
    for (int i = 0; i < 3; i++) { v[i] = xr[t + 256 * i]; s1 += v[i]; s2 += v[i] * v[i]; }
#pragma unroll
    for (int off = 32; off > 0; off >>= 1) { s1 += __shfl_down(s1, off); s2 += __shfl_down(s2, off); }
    __shared__ float sa[4], sb[4];
    int wid = t >> 6, lane = t & 63;
    if (lane == 0) { sa[wid] = s1; sb[wid] = s2; }
    __syncthreads();
    if (t == 0) { sa[0] = sa[0] + sa[1] + sa[2] + sa[3]; sb[0] = sb[0] + sb[1] + sb[2] + sb[3]; }
    __syncthreads();
    float mu = sa[0] * (1.f / D_);
    float var = sb[0] * (1.f / D_) - mu * mu;
    float rs = rsqrtf(var + 1e-5f);
#pragma unroll
    for (int i = 0; i < 3; i++) {
        int c = t + 256 * i;
        on[c] = f2b((v[i] - mu) * rs * w[c] + b[c]);
    }
}

// ---------------- MFMA GEMM 1: xz = xn @ W_in, M=8192 N=3072 K=768 ----------------
// double-buffered LDS, 1 barrier/K-step: stage(next) -> compute(cur) -> sync
__global__ __launch_bounds__(256) void gemm_in_mfma(const bf16* __restrict__ A,
                                                    const bf16* __restrict__ Bt,
                                                    bf16* __restrict__ u_pre,
                                                    bf16* __restrict__ z_s) {
    const int K = D_;
    constexpr int KT = D_ / 32;                   // 24 K-steps
    constexpr int NX = (2 * DI_) / 128;           // 24
    constexpr int NWG = NX * (ROWS_ / 128);       // 1536
    __shared__ __align__(16) short As[2][128 * 32];
    __shared__ __align__(16) short Bs[2][128 * 32];
    int tid = threadIdx.x;
    int lane = tid & 63, wid = tid >> 6;
    int wr = wid >> 1, wc = wid & 1;          // 2x2 wave grid, each wave 64x64
    int bid = blockIdx.y * NX + blockIdx.x;
    bid = (bid & 7) * (NWG / 8) + (bid >> 3);   // bijective XCD swizzle
    int m0 = (bid / NX) * 128, n0 = (bid % NX) * 128;
    f32x4 acc[4][4];
#pragma unroll
    for (int i = 0; i < 4; i++)
#pragma unroll
        for (int j = 0; j < 4; j++) acc[i][j] = (f32x4){0.f, 0.f, 0.f, 0.f};

    int rl = lane & 15;
    int kb = (lane >> 4) * 8;
    int sr = tid >> 2, sg = (tid & 3) * 8;        // staging row/chunk for this thread

    // prologue: stage tile 0 into buffer 0
#pragma unroll
    for (int c = 0; c < 2; c++) {
        gload_lds16(A + (size_t)(m0 + c * 64 + sr) * K + 0 + sg, &As[0][(c * 256 + wid * 64) * 8]);
        gload_lds16(Bt + (size_t)(n0 + c * 64 + sr) * K + 0 + sg, &Bs[0][(c * 256 + wid * 64) * 8]);
    }
    __syncthreads();

    for (int kt = 0; kt < KT; kt++) {
        int cur = kt & 1;
        if (kt + 1 < KT) {
            int k1 = (kt + 1) * 32;
#pragma unroll
            for (int c = 0; c < 2; c++) {
                gload_lds16(A + (size_t)(m0 + c * 64 + sr) * K + k1 + sg, &As[cur ^ 1][(c * 256 + wid * 64) * 8]);
                gload_lds16(Bt + (size_t)(n0 + c * 64 + sr) * K + k1 + sg, &Bs[cur ^ 1][(c * 256 + wid * 64) * 8]);
            }
        }
        bf16x8 av[4], bv[4];
#pragma unroll
        for (int i = 0; i < 4; i++)
            av[i] = *(const bf16x8*)&As[cur][(wr * 64 + i * 16 + rl) * 32 + kb];
#pragma unroll
        for (int j = 0; j < 4; j++)
            bv[j] = *(const bf16x8*)&Bs[cur][(wc * 64 + j * 16 + rl) * 32 + kb];
#pragma unroll
        for (int i = 0; i < 4; i++)
#pragma unroll
            for (int j = 0; j < 4; j++)
                acc[i][j] = __builtin_amdgcn_mfma_f32_16x16x32_bf16(av[i], bv[j], acc[i][j], 0, 0, 0);
        __syncthreads();   // drains this wave's prefetch (vmcnt0) AFTER compute
    }
#pragma unroll
    for (int i = 0; i < 4; i++) {
        int mrow = m0 + wr * 64 + i * 16 + (lane >> 4) * 4;
#pragma unroll
        for (int j = 0; j < 4; j++) {
            int ncol = n0 + wc * 64 + j * 16 + rl;
#pragma unroll
            for (int r = 0; r < 4; r++) {
                float v = acc[i][j][r];
                int m = mrow + r;
                if (ncol < DI_) u_pre[(size_t)m * DI_ + ncol] = f2b(v);
                else            z_s[(size_t)m * DI_ + (ncol - DI_)] = f2b(silu_f(v));
            }
        }
    }
}

// ---------------- MFMA GEMM 2: out = x + 0.5*(g_f+g_b) @ W_out, M=8192 N=768 K=1536 ----------------
// dbuf; A-side T14 split: issue loads early, convert+ds_write after MFMA
__global__ __launch_bounds__(256) void gemm_out_mfma(const bf16* __restrict__ gf,
                                                     const bf16* __restrict__ gb,
                                                     const bf16* __restrict__ Bt,   // [768][1536]
                                                     const float* __restrict__ resid,
                                                     float* __restrict__ C) {
    const int K = DI_, N = D_;
    constexpr int KT = DI_ / 32;                  // 48
    constexpr int NX = D_ / 128;                  // 6
    constexpr int NWG = NX * (ROWS_ / 128);       // 384
    __shared__ __align__(16) short As[2][128 * 32];
    __shared__ __align__(16) short Bs[2][128 * 32];
    int tid = threadIdx.x;
    int lane = tid & 63, wid = tid >> 6;
    int wr = wid >> 1, wc = wid & 1;
    int bid = blockIdx.y * NX + blockIdx.x;
    bid = (bid & 7) * (NWG / 8) + (bid >> 3);
    int m0 = (bid / NX) * 128, n0 = (bid % NX) * 128;
    f32x4 acc[4][4];
#pragma unroll
    for (int i = 0; i < 4; i++)
#pragma unroll
        for (int j = 0; j < 4; j++) acc[i][j] = (f32x4){0.f, 0.f, 0.f, 0.f};

    int rl = lane & 15;
    int kb = (lane >> 4) * 8;
    int sr = tid >> 2, sg = (tid & 3) * 8;

    auto conv_store = [&](int buf, ushort4 a0, ushort4 a1, ushort4 b0, ushort4 b1, int c) {
        bf16x8 st;
        st[0] = f2bbits(bfb(a0.x) + bfb(b0.x));
        st[1] = f2bbits(bfb(a0.y) + bfb(b0.y));
        st[2] = f2bbits(bfb(a0.z) + bfb(b0.z));
        st[3] = f2bbits(bfb(a0.w) + bfb(b0.w));
        st[4] = f2bbits(bfb(a1.x) + bfb(b1.x));
        st[5] = f2bbits(bfb(a1.y) + bfb(b1.y));
        st[6] = f2bbits(bfb(a1.z) + bfb(b1.z));
        st[7] = f2bbits(bfb(a1.w) + bfb(b1.w));
        *(bf16x8*)&As[buf][(c * 256 + tid) * 8] = st;
    };

    // prologue: stage K-tile 0 into buffer 0
    {
#pragma unroll
        for (int c = 0; c < 2; c++) {
            size_t off = (size_t)(m0 + c * 64 + sr) * K + 0 + sg;
            const unsigned short* pf = (const unsigned short*)(gf + off);
            const unsigned short* pb = (const unsigned short*)(gb + off);
            ushort4 a0 = *(const ushort4*)pf, a1 = *(const ushort4*)(pf + 4);
            ushort4 b0 = *(const ushort4*)pb, b1 = *(const ushort4*)(pb + 4);
            conv_store(0, a0, a1, b0, b1, c);
            gload_lds16(Bt + (size_t)(n0 + c * 64 + sr) * K + 0 + sg, &Bs[0][(c * 256 + wid * 64) * 8]);
        }
    }
    __syncthreads();

    for (int kt = 0; kt < KT; kt++) {
        int cur = kt & 1;
        ushort4 ra0[2], ra1[2], rb0[2], rb1[2];
        if (kt + 1 < KT) {
            int k1 = (kt + 1) * 32;
#pragma unroll
            for (int c = 0; c < 2; c++) {
                size_t off = (size_t)(m0 + c * 64 + sr) * K + k1 + sg;
                const unsigned short* pf = (const unsigned short*)(gf + off);
                const unsigned short* pb = (const unsigned short*)(gb + off);
                ra0[c] = *(const ushort4*)pf; ra1[c] = *(const ushort4*)(pf + 4);
                rb0[c] = *(const ushort4*)pb; rb1[c] = *(const ushort4*)(pb + 4);
                gload_lds16(Bt + (size_t)(n0 + c * 64 + sr) * K + k1 + sg, &Bs[cur ^ 1][(c * 256 + wid * 64) * 8]);
            }
        }
        bf16x8 av[4], bv[4];
#pragma unroll
        for (int i = 0; i < 4; i++)
            av[i] = *(const bf16x8*)&As[cur][(wr * 64 + i * 16 + rl) * 32 + kb];
#pragma unroll
        for (int j = 0; j < 4; j++)
            bv[j] = *(const bf16x8*)&Bs[cur][(wc * 64 + j * 16 + rl) * 32 + kb];
#pragma unroll
        for (int i = 0; i < 4; i++)
#pragma unroll
            for (int j = 0; j < 4; j++)
                acc[i][j] = __builtin_amdgcn_mfma_f32_16x16x32_bf16(av[i], bv[j], acc[i][j], 0, 0, 0);
        if (kt + 1 < KT) {
#pragma unroll
            for (int c = 0; c < 2; c++)
                conv_store(cur ^ 1, ra0[c], ra1[c], rb0[c], rb1[c], c);
        }
        __syncthreads();
    }
#pragma unroll
    for (int i = 0; i < 4; i++) {
        int mrow = m0 + wr * 64 + i * 16 + (lane >> 4) * 4;
#pragma unroll
        for (int j = 0; j < 4; j++) {
            int ncol = n0 + wc * 64 + j * 16 + rl;
#pragma unroll
            for (int r = 0; r < 4; r++) {
                size_t idx = (size_t)(mrow + r) * N + ncol;
                C[idx] = resid[idx] + 0.5f * acc[i][j][r];
            }
        }
    }
}

// ---------------- conv(4) + silu, both dirs, 8 channels/thread (bf16x8) ----------------
__global__ __launch_bounds__(256) void conv_kernel8(const bf16* __restrict__ up,
                                                    const float* __restrict__ cw,
                                                    const float* __restrict__ cb,
                                                    bf16* __restrict__ uf,
                                                    bf16* __restrict__ ub) {
    const int dpb = DI_ / 8;                       // 192 thread-groups per row
    int idx = blockIdx.x * 256 + threadIdx.x;      // over ROWS_*DI_/8
    int d8 = (idx % dpb) * 8;
    int bl = idx / dpb;
    int l = bl % L_, b = bl / L_;
    const bf16* base = up + (size_t)b * L_ * DI_ + d8;
    float um[7][8];
#pragma unroll
    for (int k = 0; k < 7; k++) {
        int ll = l - 3 + k;
        if (ll >= 0 && ll < L_) {
            bf16x8 v = *(const bf16x8*)(base + (size_t)ll * DI_);
#pragma unroll
            for (int e = 0; e < 8; e++) um[k][e] = bfb((unsigned short)v[e]);
        } else {
#pragma unroll
            for (int e = 0; e < 8; e++) um[k][e] = 0.f;
        }
    }
    bf16x8 of, ob;
#pragma unroll
    for (int e = 0; e < 8; e++) {
        float4 w = *(const float4*)(cw + (size_t)(d8 + e) * 4);
        float bias = cb[d8 + e];
        float cf  = bias + um[0][e] * w.x + um[1][e] * w.y + um[2][e] * w.z + um[3][e] * w.w;
        float cbw = bias + um[6][e] * w.x + um[5][e] * w.y + um[4][e] * w.z + um[3][e] * w.w;
        of[e] = f2bbits(silu_f(cf));
        ob[e] = f2bbits(silu_f(cbw));
    }
    size_t oidx = (size_t)bl * DI_ + d8;
    *(bf16x8*)(uf + oidx) = of;
    *(bf16x8*)(ub + oidx) = ob;
}

// ---------------- MFMA xdb: u @ W_x -> BC cols fp32 + dt_raw bf16 padded ----------------
// double-buffered A staging (1 wave/SIMD kernel -> prefetch is the only latency cover)
__global__ __launch_bounds__(256) void xdb_mfma(const bf16* __restrict__ uf,
                                                const bf16* __restrict__ ub,
                                                const bf16* __restrict__ Wxt,   // [80][1536]
                                                float* __restrict__ xf,
                                                float* __restrict__ xb,
                                                bf16* __restrict__ drf,         // [ROWS][64]
                                                bf16* __restrict__ drb) {
    const bf16* u = blockIdx.y ? ub : uf;
    float* xout = blockIdx.y ? xb : xf;
    bf16* dout = blockIdx.y ? drb : drf;
    int m0 = blockIdx.x * 64;
    constexpr int KT = DI_ / 64;                  // 24
    __shared__ __align__(16) short As[2][64 * 64];
    int tid = threadIdx.x;
    int lane = tid & 63, wid = tid >> 6;
    int rl = lane & 15, hi = lane >> 4;
    f32x4 acc[5];
#pragma unroll
    for (int j = 0; j < 5; j++) acc[j] = (f32x4){0.f, 0.f, 0.f, 0.f};

    int r_loc = wid * 16 + rl;
    int srow = tid >> 3, schunk = tid & 7;
    int scs = schunk ^ (srow & 7);                // pre-swizzled source chunk

    // prologue
#pragma unroll
    for (int t = 0; t < 2; t++)
        gload_lds16(u + (size_t)(m0 + t * 32 + srow) * DI_ + 0 + ((schunk ^ ((t * 32 + srow) & 7)) * 8)
                        - ((schunk ^ (srow & 7)) * 8) + scs * 8,   // == swizzle of actual row
                    &As[0][(t * 256 + wid * 64) * 8]);
    __syncthreads();

    for (int kt = 0; kt < KT; kt++) {
        int cur = kt & 1;
        if (kt + 1 < KT) {
            int k1 = (kt + 1) * 64;
#pragma unroll
            for (int t = 0; t < 2; t++) {
                int row = t * 32 + srow;
                int cs = schunk ^ (row & 7);
                gload_lds16(u + (size_t)(m0 + row) * DI_ + k1 + cs * 8,
                            &As[cur ^ 1][(t * 256 + wid * 64) * 8]);
            }
        }
        int k0 = kt * 64;
        bf16x8 av[2];
#pragma unroll
        for (int kc = 0; kc < 2; kc++) {
            int c = kc * 4 + hi;
            av[kc] = *(const bf16x8*)&As[cur][r_loc * 64 + ((c ^ (r_loc & 7)) * 8)];
        }
#pragma unroll
        for (int j = 0; j < 5; j++)
#pragma unroll
            for (int kc = 0; kc < 2; kc++) {
                bf16x8 bv = *(const bf16x8*)(Wxt + (size_t)(j * 16 + rl) * DI_ + k0 + kc * 32 + hi * 8);
                acc[j] = __builtin_amdgcn_mfma_f32_16x16x32_bf16(av[kc], bv, acc[j], 0, 0, 0);
            }
        __syncthreads();
    }
#pragma unroll
    for (int j = 0; j < 5; j++) {
        int col = j * 16 + rl;
#pragma unroll
        for (int r = 0; r < 4; r++) {
            int m = m0 + wid * 16 + hi * 4 + r;
            float v = acc[j][r];
            if (col >= DTR_) xout[(size_t)m * 80 + col] = v;          // B,C cols for scan
            if (col < DTR_)      dout[(size_t)m * 64 + col] = f2b(v); // dt_raw
            else if (col < 64)   dout[(size_t)m * 64 + col] = f2b(0.f); // K-pad zeros
        }
    }
}

// ---------------- MFMA dt: softplus(dt_raw @ W_dt + b), M=8192 N=1536 K=64(pad) ----------------
__global__ __launch_bounds__(256) void gemm_dt_mfma(const bf16* __restrict__ drf,
                                                    const bf16* __restrict__ drb,
                                                    const bf16* __restrict__ Wdt_t, // [1536][64]
                                                    const float* __restrict__ bdt,
                                                    bf16* __restrict__ dtf,
                                                    bf16* __restrict__ dtb) {
    const bf16* A = blockIdx.z ? drb : drf;
    bf16* out = blockIdx.z ? dtb : dtf;
    int m0 = blockIdx.y * 64;
    int n0 = blockIdx.x * 256;
    __shared__ __align__(16) short As[64 * 64];
    int tid = threadIdx.x, lane = tid & 63, wid = tid >> 6;
    int rl = lane & 15, hi = lane >> 4;
#pragma unroll
    for (int t = 0; t < 2; t++) {
        int s = t * 256 + tid;
        int row = s >> 3, c = s & 7;
        gload_lds16(A + (size_t)(m0 + row) * 64 + (c ^ (row & 7)) * 8,
                    &As[(t * 256 + wid * 64) * 8]);
    }
    __syncthreads();
    int r_loc = wid * 16 + rl;
    bf16x8 av[2];
#pragma unroll
    for (int kc = 0; kc < 2; kc++) {
        int c = kc * 4 + hi;
        av[kc] = *(const bf16x8*)&As[r_loc * 64 + ((c ^ (r_loc & 7)) * 8)];
    }
    f32x4 acc[16];
#pragma unroll
    for (int j = 0; j < 16; j++) acc[j] = (f32x4){0.f, 0.f, 0.f, 0.f};
#pragma unroll
    for (int j = 0; j < 16; j++)
#pragma unroll
        for (int kc = 0; kc < 2; kc++) {
            bf16x8 bv = *(const bf16x8*)(Wdt_t + (size_t)(n0 + j * 16 + rl) * 64 + kc * 32 + hi * 8);
            acc[j] = __builtin_amdgcn_mfma_f32_16x16x32_bf16(av[kc], bv, acc[j], 0, 0, 0);
        }
#pragma unroll
    for (int j = 0; j < 16; j++) {
        int n = n0 + j * 16 + rl;
        float bb = bdt[n];
#pragma unroll
        for (int r = 0; r < 4; r++) {
            int m = m0 + wid * 16 + hi * 4 + r;
            out[(size_t)m * DI_ + n] = f2b(softplus_f(acc[j][r] + bb));
        }
    }
}

// ================= chunked parallel scan (round-10: packed fp32, incremental pointers) =================
__global__ __launch_bounds__(256) void scan_part1(const bf16* __restrict__ dtf,
                                                  const bf16* __restrict__ dtb,
                                                  const bf16* __restrict__ uff,
                                                  const bf16* __restrict__ ubb,
                                                  const float* __restrict__ xdbf,
                                                  const float* __restrict__ xdbb,
                                                  const float* __restrict__ A_log,
                                                  float* __restrict__ Pbuf,
                                                  float* __restrict__ Ebuf,
                                                  int NC, int CL) {
    int dir = blockIdx.z;
    int b = blockIdx.y / NC, c = blockIdx.y % NC;
    int d = blockIdx.x * 256 + threadIdx.x;
    size_t cbase = (size_t)b * L_ * DI_ + d;
    const bf16* dt = (dir ? dtb : dtf) + cbase;
    const bf16* uu = (dir ? ubb : uff) + cbase;
    const float* xdb = (dir ? xdbb : xdbf) + (size_t)b * L_ * 80;

    float a[DS_];
    int fast = 1;
#pragma unroll
    for (int s = 0; s < DS_; s++) {
        a[s] = -__expf(A_log[d * DS_ + s]);
        fast = fast && (fabsf(a[s] + (float)(s + 1)) < 1e-4f * (s + 1));
    }
    fast = __syncthreads_and(fast);

    int t0 = c * CL;
    int l0 = dir ? (L_ - 1 - t0) : t0;
    int sD = dir ? -DI_ : DI_;
    int s80 = dir ? -80 : 80;
    const bf16* pdt = dt + (size_t)l0 * DI_;
    const bf16* pu  = uu + (size_t)l0 * DI_;
    const float* pbr = xdb + (size_t)l0 * 80 + DTR_;

    size_t base = (((size_t)(dir * B_ + b) * NC + c) * DS_) * DI_ + d;

    if (fast) {
        f32x2 h2[8];
#pragma unroll
        for (int k = 0; k < 8; k++) h2[k] = (f32x2){0.f, 0.f};
        float sdt = 0.f;
        for (int it = 0; it < CL; ++it) {
            float dtv = b2f(*pdt);
            float uv  = b2f(*pu);
            float xu = dtv * uv;
            sdt += dtv;
            float r = __expf(-dtv);
            f32x2 pw[8]; pow_tree(r, pw);
            float4 b0 = *(const float4*)(pbr);
            float4 b1 = *(const float4*)(pbr + 4);
            float4 b2v = *(const float4*)(pbr + 8);
            float4 b3 = *(const float4*)(pbr + 12);
            f32x2 B2[8] = {{b0.x, b0.y}, {b0.z, b0.w}, {b1.x, b1.y}, {b1.z, b1.w},
                           {b2v.x, b2v.y}, {b2v.z, b2v.w}, {b3.x, b3.y}, {b3.z, b3.w}};
            f32x2 xu2 = {xu, xu};
#pragma unroll
            for (int k = 0; k < 8; k++) h2[k] = h2[k] * pw[k] + xu2 * B2[k];
            pdt += sD; pu += sD; pbr += s80;
        }
        float Rc = __expf(-sdt);
        f32x2 pwP[8]; pow_tree(Rc, pwP);
#pragma unroll
        for (int k = 0; k < 8; k++) {
            Pbuf[base + (size_t)(2 * k) * DI_]     = pwP[k].x;
            Pbuf[base + (size_t)(2 * k + 1) * DI_] = pwP[k].y;
            Ebuf[base + (size_t)(2 * k) * DI_]     = h2[k].x;
            Ebuf[base + (size_t)(2 * k + 1) * DI_] = h2[k].y;
        }
    } else {
        float h[DS_], P[DS_];
#pragma unroll
        for (int s = 0; s < DS_; s++) { h[s] = 0.f; P[s] = 1.f; }
        for (int it = 0; it < CL; ++it) {
            float dtv = b2f(*pdt);
            float uv = b2f(*pu);
            float xu = dtv * uv;
            float4 b0 = *(const float4*)(pbr);
            float4 b1 = *(const float4*)(pbr + 4);
            float4 b2v = *(const float4*)(pbr + 8);
            float4 b3 = *(const float4*)(pbr + 12);
            float Bv[16] = {b0.x, b0.y, b0.z, b0.w, b1.x, b1.y, b1.z, b1.w,
                            b2v.x, b2v.y, b2v.z, b2v.w, b3.x, b3.y, b3.z, b3.w};
#pragma unroll
            for (int s = 0; s < DS_; s++) {
                float dA = __expf(dtv * a[s]);
                h[s] = h[s] * dA + xu * Bv[s];
                P[s] *= dA;
            }
            pdt += sD; pu += sD; pbr += s80;
        }
#pragma unroll
        for (int s = 0; s < DS_; s++) {
            Pbuf[base + (size_t)s * DI_] = P[s];
            Ebuf[base + (size_t)s * DI_] = h[s];
        }
    }
}

__global__ __launch_bounds__(256) void scan_part2(const float* __restrict__ Pbuf,
                                                  float* __restrict__ Ebuf,
                                                  int NC) {
    int idx = blockIdx.x * 256 + threadIdx.x;   // over 2*B*DS*DI
    int d = idx % DI_;
    int rest = idx / DI_;
    int s = rest % DS_;
    int bb = rest / DS_;                        // dir*B + b
    size_t base = ((size_t)bb * NC * DS_ + s) * DI_ + d;
    float H = 0.f;
    for (int c = 0; c < NC; c++) {
        size_t aa = base + (size_t)c * DS_ * DI_;
        float P = Pbuf[aa], E = Ebuf[aa];
        Ebuf[aa] = H;
        H = P * H + E;
    }
}

__global__ __launch_bounds__(256) void scan_part3(const bf16* __restrict__ dtf,
                                                  const bf16* __restrict__ dtb,
                                                  const bf16* __restrict__ uff,
                                                  const bf16* __restrict__ ubb,
                                                  const float* __restrict__ xdbf,
                                                  const float* __restrict__ xdbb,
                                                  const bf16* __restrict__ z_s,
                                                  const float* __restrict__ A_log,
                                                  const float* __restrict__ Dp_,
                                                  const float* __restrict__ Ebuf,
                                                  bf16* __restrict__ gf,
                                                  bf16* __restrict__ gb,
                                                  int NC, int CL) {
    int dir = blockIdx.z;
    int b = blockIdx.y / NC, c = blockIdx.y % NC;
    int d = blockIdx.x * 256 + threadIdx.x;
    size_t cbase = (size_t)b * L_ * DI_ + d;
    const bf16* dt = (dir ? dtb : dtf) + cbase;
    const bf16* uu = (dir ? ubb : uff) + cbase;
    const float* xdb = (dir ? xdbb : xdbf) + (size_t)b * L_ * 80;
    const bf16* zp = z_s + cbase;
    bf16* g = (dir ? gb : gf) + cbase;

    float a[DS_];
    int fast = 1;
#pragma unroll
    for (int s = 0; s < DS_; s++) {
        a[s] = -__expf(A_log[d * DS_ + s]);
        fast = fast && (fabsf(a[s] + (float)(s + 1)) < 1e-4f * (s + 1));
    }
    fast = __syncthreads_and(fast);
    float Dp = Dp_[d];

    size_t base = (((size_t)(dir * B_ + b) * NC + c) * DS_) * DI_ + d;

    int t0 = c * CL;
    int l0 = dir ? (L_ - 1 - t0) : t0;
    int sD = dir ? -DI_ : DI_;
    int s80 = dir ? -80 : 80;
    const bf16* pdt = dt + (size_t)l0 * DI_;
    const bf16* pu  = uu + (size_t)l0 * DI_;
    const bf16* pz  = zp + (size_t)l0 * DI_;
    bf16* pg = g + (size_t)l0 * DI_;
    const float* pbr = xdb + (size_t)l0 * 80 + DTR_;

    if (fast) {
        f32x2 h2[8];
#pragma unroll
        for (int k = 0; k < 8; k++)
            h2[k] = (f32x2){Ebuf[base + (size_t)(2 * k) * DI_],
                            Ebuf[base + (size_t)(2 * k + 1) * DI_]};
        for (int it = 0; it < CL; ++it) {
            float dtv = b2f(*pdt);
            float uv  = b2f(*pu);
            float zv  = b2f(*pz);
            float xu = dtv * uv;
            float r = __expf(-dtv);
            f32x2 pw[8]; pow_tree(r, pw);
            float4 b0 = *(const float4*)(pbr);
            float4 b1 = *(const float4*)(pbr + 4);
            float4 b2v = *(const float4*)(pbr + 8);
            float4 b3 = *(const float4*)(pbr + 12);
            float4 c0 = *(const float4*)(pbr + 16);
            float4 c1 = *(const float4*)(pbr + 20);
            float4 c2v = *(const float4*)(pbr + 24);
            float4 c3 = *(const float4*)(pbr + 28);
            f32x2 B2[8] = {{b0.x, b0.y}, {b0.z, b0.w}, {b1.x, b1.y}, {b1.z, b1.w},
                           {b2v.x, b2v.y}, {b2v.z, b2v.w}, {b3.x, b3.y}, {b3.z, b3.w}};
            f32x2 C2[8] = {{c0.x, c0.y}, {c0.z, c0.w}, {c1.x, c1.y}, {c1.z, c1.w},
                           {c2v.x, c2v.y}, {c2v.z, c2v.w}, {c3.x, c3.y}, {c3.z, c3.w}};
            f32x2 xu2 = {xu, xu};
            f32x2 y2 = {0.f, 0.f};
#pragma unroll
            for (int k = 0; k < 8; k++) {
                h2[k] = h2[k] * pw[k] + xu2 * B2[k];
                y2 = y2 + h2[k] * C2[k];
            }
            float y = y2.x + y2.y;
            *pg = f2b((y + uv * Dp) * zv);
            pdt += sD; pu += sD; pz += sD; pg += sD; pbr += s80;
        }
    } else {
        float h[DS_];
#pragma unroll
        for (int s = 0; s < DS_; s++) h[s] = Ebuf[base + (size_t)s * DI_];
        for (int it = 0; it < CL; ++it) {
            float dtv = b2f(*pdt);
            float uv = b2f(*pu);
            float zv = b2f(*pz);
            float xu = dtv * uv;
            float4 b0 = *(const float4*)(pbr);
            float4 b1 = *(const float4*)(pbr + 4);
            float4 b2v = *(const float4*)(pbr + 8);
            float4 b3 = *(const float4*)(pbr + 12);
            float4 c0 = *(const float4*)(pbr + 16);
            float4 c1 = *(const float4*)(pbr + 20);
            float4 c2v = *(const float4*)(pbr + 24);
            float4 c3 = *(const float4*)(pbr + 28);
            float Bv[16] = {b0.x, b0.y, b0.z, b0.w, b1.x, b1.y, b1.z, b1.w,
                            b2v.x, b2v.y, b2v.z, b2v.w, b3.x, b3.y, b3.z, b3.w};
            float Cv[16] = {c0.x, c0.y, c0.z, c0.w, c1.x, c1.y, c1.z, c1.w,
                            c2v.x, c2v.y, c2v.z, c2v.w, c3.x, c3.y, c3.z, c3.w};
            float y = 0.f;
#pragma unroll
            for (int s = 0; s < DS_; s++) {
                float dA = __expf(dtv * a[s]);
                h[s] = h[s] * dA + xu * Bv[s];
                y += h[s] * Cv[s];
            }
            *pg = f2b((y + uv * Dp) * zv);
            pdt += sD; pu += sD; pz += sD; pg += sD; pbr += s80;
        }
    }
}

// ---------------- legacy single-pass scan (ws fallback) ----------------
__global__ __launch_bounds__(256) void scan_kernel(const bf16* __restrict__ dtf,
                                                   const bf16* __restrict__ dtb,
                                                   const bf16* __restrict__ uff,
                                                   const bf16* __restrict__ ubb,
                                                   const float* __restrict__ xdbf,
                                                   const float* __restrict__ xdbb,
                                                   const bf16* __restrict__ z_s,
                                                   const float* __restrict__ A_log,
                                                   const float* __restrict__ Dp_,
                                                   bf16* __restrict__ gf,
                                                   bf16* __restrict__ gb) {
    int dir = blockIdx.z;
    int b = blockIdx.y;
    int d = blockIdx.x * 256 + threadIdx.x;
    size_t cbase = (size_t)b * L_ * DI_ + d;
    const bf16* dt = (dir ? dtb : dtf) + cbase;
    const bf16* uu = (dir ? ubb : uff) + cbase;
    const float* xdb = (dir ? xdbb : xdbf) + (size_t)b * L_ * 80;
    const bf16* zp = z_s + cbase;
    bf16* g = (dir ? gb : gf) + cbase;
    float a[DS_];
#pragma unroll
    for (int s = 0; s < DS_; s++) a[s] = -__expf(A_log[d * DS_ + s]);
    float Dp = Dp_[d];
    float h[DS_];
#pragma unroll
    for (int s = 0; s < DS_; s++) h[s] = 0.f;
    for (int tt = 0; tt < L_; ++tt) {
        int l = dir ? (L_ - 1 - tt) : tt;
        size_t off = (size_t)l * DI_;
        float dtv = b2f(dt[off]);
        float uv = b2f(uu[off]);
        float zv = b2f(zp[off]);
        float xu = dtv * uv;
        const float* br = xdb + (size_t)l * 80 + DTR_;
        float y = 0.f;
#pragma unroll
        for (int s = 0; s < DS_; s++) {
            float dA = __expf(dtv * a[s]);
            h[s] = h[s] * dA + xu * br[s];
            y += h[s] * br[16 + s];
        }
        g[off] = f2b((y + uv * Dp) * zv);
    }
}

extern "C" void kernel_launch(void* const* d_in, const int* in_sizes, int n_in,
                              void* d_out, int out_size, void* d_ws, size_t ws_size,
                              hipStream_t stream) {
    const float* x      = (const float*)d_in[0];
    const float* ln_w   = (const float*)d_in[1];
    const float* ln_b   = (const float*)d_in[2];
    const float* W_in   = (const float*)d_in[3];
    const float* conv_w = (const float*)d_in[4];
    const float* conv_b = (const float*)d_in[5];
    const float* W_x    = (const float*)d_in[6];
    const float* W_dt   = (const float*)d_in[7];
    const float* b_dt   = (const float*)d_in[8];
    const float* A_log  = (const float*)d_in[9];
    const float* D_par  = (const float*)d_in[10];
    const float* W_out  = (const float*)d_in[11];
    float* out = (float*)d_out;

    const size_t NBbf = (size_t)ROWS_ * DI_ * sizeof(bf16);     // 25,165,824 B
    const size_t XDB4 = (size_t)ROWS_ * 80 * sizeof(float);     //  2,621,440 B
    const size_t WT1  = (size_t)D_ * 2 * DI_ * sizeof(bf16);    //  4,718,592 B
    const size_t WT2  = (size_t)DI_ * D_ * sizeof(bf16);        //  2,359,296 B
    const size_t WXT  = (size_t)80 * DI_ * sizeof(bf16);        //    245,760 B
    const size_t WDT  = (size_t)DI_ * 64 * sizeof(bf16);        //    196,608 B
    const size_t DR   = (size_t)ROWS_ * 64 * sizeof(bf16);      //  1,048,576 B
    const size_t BASE = 7 * NBbf + 2 * XDB4 + WT1 + WT2 + WXT + WDT + 2 * DR;
    if (ws_size < BASE) return;  // diagnostic: absmax-fail instead of GPU fault

    auto pe_bytes = [&](int NC) { return (size_t)2 * B_ * NC * DS_ * DI_ * sizeof(float); };
    int NC = 0;
    if (ws_size >= BASE + 2 * pe_bytes(32)) NC = 32;
    else if (ws_size >= BASE + 2 * pe_bytes(16)) NC = 16;
    const int CL = NC ? L_ / NC : 0;

    char* p = (char*)d_ws;
    bf16* z_s   = (bf16*)p;  p += NBbf;
    bf16* u_f   = (bf16*)p;  p += NBbf;
    bf16* u_b   = (bf16*)p;  p += NBbf;
    bf16* slotA = (bf16*)p;  p += NBbf;   // u_pre [gemm_in..conv] / dt_f [gemm_dt..scan]
    bf16* dt_b  = (bf16*)p;  p += NBbf;
    char* slotB = p;         p += NBbf;   // xn bf16 [ln..gemm_in] / g_f bf16 [scan..gemm_out]
    bf16* g_b   = (bf16*)p;  p += NBbf;
    float* xdb_f = (float*)p; p += XDB4;
    float* xdb_b = (float*)p; p += XDB4;
    bf16* Wt_in  = (bf16*)p;  p += WT1;   // [3072][768]
    bf16* Wt_out = (bf16*)p;  p += WT2;   // [768][1536]
    bf16* Wxt    = (bf16*)p;  p += WXT;   // [80][1536]
    bf16* Wdt_t  = (bf16*)p;  p += WDT;   // [1536][64]
    bf16* dr_f   = (bf16*)p;  p += DR;    // [8192][64]
    bf16* dr_b   = (bf16*)p;  p += DR;
    float* Pbuf = (float*)p;  p += NC ? pe_bytes(NC) : 0;
    float* Ebuf = (float*)p;

    bf16* u_pre = slotA;
    bf16* dt_f  = slotA;
    bf16* xn    = (bf16*)slotB;
    bf16* g_f   = (bf16*)slotB;

    // 0. weight conversions (independent of LN)
    convert_wt<<<dim3((2 * DI_) / 32, D_ / 32), 256, 0, stream>>>(W_in, Wt_in, D_, 2 * DI_);
    convert_wt<<<dim3(D_ / 32, DI_ / 32), 256, 0, stream>>>(W_out, Wt_out, DI_, D_);
    convert_wxt<<<(80 * DI_) / 256, 256, 0, stream>>>(W_x, Wxt);
    convert_wdt<<<(DI_ * 64) / 256, 256, 0, stream>>>(W_dt, Wdt_t);
    // 1. layernorm -> bf16
    ln_kernel<<<ROWS_, 256, 0, stream>>>(x, ln_w, ln_b, xn);
    // 2. xz = xn @ W_in (MFMA dbuf); u half -> bf16, z half -> silu -> bf16
    gemm_in_mfma<<<dim3((2 * DI_) / 128, ROWS_ / 128), 256, 0, stream>>>(xn, Wt_in, u_pre, z_s);
    // 3. conv + silu, both dirs (8 ch/thread)
    conv_kernel8<<<(ROWS_ * DI_ / 8) / 256, 256, 0, stream>>>(u_pre, conv_w, conv_b, u_f, u_b);
    // 4. xdb = u @ W_x (MFMA dbuf), both dirs; BC cols fp32 + dt_raw bf16 padded
    xdb_mfma<<<dim3(ROWS_ / 64, 2), 256, 0, stream>>>(u_f, u_b, Wxt, xdb_f, xdb_b, dr_f, dr_b);
    // 5. dt = softplus(dt_raw @ W_dt + b_dt) (MFMA), both dirs
    gemm_dt_mfma<<<dim3(DI_ / 256, ROWS_ / 64, 2), 256, 0, stream>>>(dr_f, dr_b, Wdt_t, b_dt, dt_f, dt_b);
    // 6. SSM scan (round-10 1-ch/thread)
    if (NC) {
        scan_part1<<<dim3(DI_ / 256, B_ * NC, 2), 256, 0, stream>>>(
            dt_f, dt_b, u_f, u_b, xdb_f, xdb_b, A_log, Pbuf, Ebuf, NC, CL);
        scan_part2<<<(2 * B_ * DS_ * DI_) / 256, 256, 0, stream>>>(Pbuf, Ebuf, NC);
        scan_part3<<<dim3(DI_ / 256, B_ * NC, 2), 256, 0, stream>>>(
            dt_f, dt_b, u_f, u_b, xdb_f, xdb_b, z_s, A_log, D_par, Ebuf, g_f, g_b, NC, CL);
    } else {
        scan_kernel<<<dim3(DI_ / 256, B_, 2), 256, 0, stream>>>(
            dt_f, dt_b, u_f, u_b, xdb_f, xdb_b, z_s, A_log, D_par, g_f, g_b);
    }
    // 7. out = x + 0.5 * (g_f + g_b) @ W_out (MFMA dbuf, resid fused)
    gemm_out_mfma<<<dim3(D_ / 128, ROWS_ / 128), 256, 0, stream>>>(g_f, g_b, Wt_out, x, out);
}

// Round 15
// 378.663 us; speedup vs baseline: 1.0686x; 1.0046x over previous
//
#include <hip/hip_runtime.h>
#include <hip/hip_bf16.h>

#define B_  4
#define L_  2048
#define D_  768
#define DI_ 1536
#define DS_ 16
#define DTR_ 48
#define ROWS_ (B_*L_)   // 8192

typedef __hip_bfloat16 bf16;
typedef __attribute__((ext_vector_type(8))) short bf16x8;
typedef __attribute__((ext_vector_type(4))) float f32x4;
typedef __attribute__((ext_vector_type(2))) float f32x2;

__device__ __forceinline__ float silu_f(float x) { return x / (1.f + __expf(-x)); }
__device__ __forceinline__ float softplus_f(float x) { return x > 15.f ? x : __logf(1.f + __expf(x)); }
__device__ __forceinline__ float b2f(bf16 v) { return __bfloat162float(v); }
__device__ __forceinline__ bf16 f2b(float v) { return __float2bfloat16(v); }
__device__ __forceinline__ float bfb(unsigned short u) {
    union { unsigned int i; float f; } w; w.i = ((unsigned int)u) << 16; return w.f;
}
__device__ __forceinline__ short f2bbits(float v) {
    bf16 t = __float2bfloat16(v);
    return *(short*)&t;
}
__device__ __forceinline__ void gload_lds16(const void* g, void* l) {
    __builtin_amdgcn_global_load_lds((const __attribute__((address_space(1))) void*)g,
                                     (__attribute__((address_space(3))) void*)l, 16, 0, 0);
}

// packed powers: pw[k] = {r^(2k+1), r^(2k+2)}, depth-4 tree, 10 instrs
__device__ __forceinline__ void pow_tree(float r, f32x2 pw[8]) {
    float r2 = r * r;
    f32x2 rr = {r2, r2};
    f32x2 r4 = rr * rr;
    f32x2 r8 = r4 * r4;
    pw[0] = (f32x2){r, r2};
    pw[1] = pw[0] * rr;
    pw[2] = pw[0] * r4;
    pw[3] = pw[1] * r4;
    pw[4] = pw[0] * r8;
    pw[5] = pw[1] * r8;
    pw[6] = pw[2] * r8;
    pw[7] = pw[3] * r8;
}

// ---------------- weight convert+transpose: W[K][N] fp32 -> Wt[N][K] bf16 ----------------
__global__ __launch_bounds__(256) void convert_wt(const float* __restrict__ W,
                                                  bf16* __restrict__ Wt,
                                                  int K, int N) {
    __shared__ float tile[32][33];
    int bx = blockIdx.x * 32;          // N
    int by = blockIdx.y * 32;          // K
    int tx = threadIdx.x & 31, ty = threadIdx.x >> 5;   // 32 x 8
#pragma unroll
    for (int i = 0; i < 32; i += 8)
        tile[ty + i][tx] = W[(size_t)(by + ty + i) * N + bx + tx];
    __syncthreads();
#pragma unroll
    for (int i = 0; i < 32; i += 8)
        Wt[(size_t)(bx + ty + i) * K + by + tx] = f2b(tile[tx][ty + i]);
}

// W_x [1536][80] fp32 -> Wxt [80][1536] bf16
__global__ __launch_bounds__(256) void convert_wxt(const float* __restrict__ W,
                                                   bf16* __restrict__ Wt) {
    int idx = blockIdx.x * 256 + threadIdx.x;   // over 80*1536
    int n = idx / DI_, k = idx % DI_;
    Wt[idx] = f2b(W[(size_t)k * 80 + n]);
}

// W_dt [48][1536] fp32 -> Wdt_t [1536][64] bf16 (K-padded with zeros)
__global__ __launch_bounds__(256) void convert_wdt(const float* __restrict__ W,
                                                   bf16* __restrict__ Wt) {
    int idx = blockIdx.x * 256 + threadIdx.x;   // over 1536*64
    int n = idx >> 6, k = idx & 63;
    Wt[idx] = f2b(k < DTR_ ? W[(size_t)k * DI_ + n] : 0.f);
}

// ---------------- LayerNorm (fp32 -> bf16) ----------------
__global__ __launch_bounds__(256) void ln_kernel(const float* __restrict__ x,
                                                 const float* __restrict__ w,
                                                 const float* __restrict__ b,
                                                 bf16* __restrict__ xn) {
    int row = blockIdx.x;
    const float* xr = x + (size_t)row * D_;
    bf16* on = xn + (size_t)row * D_;
    int t = threadIdx.x;
    float v[3];
    float s1 = 0.f, s2 = 0.f;
#pragma unroll
    for (int i = 0; i < 3; i++) { v[i] = xr[t + 256 * i]; s1 += v[i]; s2 += v[i] * v[i]; }
#pragma unroll
    for (int off = 32; off > 0; off >>= 1) { s1 += __shfl_down(s1, off); s2 += __shfl_down(s2, off); }
    __shared__ float sa[4], sb[4];
    int wid = t >> 6, lane = t & 63;
    if (lane == 0) { sa[wid] = s1; sb[wid] = s2; }
    __syncthreads();
    if (t == 0) { sa[0] = sa[0] + sa[1] + sa[2] + sa[3]; sb[0] = sb[0] + sb[1] + sb[2] + sb[3]; }
    __syncthreads();
    float mu = sa[0] * (1.f / D_);
    float var = sb[0] * (1.f / D_) - mu * mu;
    float rs = rsqrtf(var + 1e-5f);
#pragma unroll
    for (int i = 0; i < 3; i++) {
        int c = t + 256 * i;
        on[c] = f2b((v[i] - mu) * rs * w[c] + b[c]);
    }
}

// ---------------- MFMA GEMM 1 (round-9 single-buffer): xz = xn @ W_in ----------------
__global__ __launch_bounds__(256) void gemm_in_mfma(const bf16* __restrict__ A,
                                                    const bf16* __restrict__ Bt,
                                                    bf16* __restrict__ u_pre,
                                                    bf16* __restrict__ z_s) {
    const int K = D_;
    constexpr int NX = (2 * DI_) / 128;           // 24
    constexpr int NWG = NX * (ROWS_ / 128);       // 1536
    __shared__ __align__(16) short As[128 * 32];
    __shared__ __align__(16) short Bs[128 * 32];
    int tid = threadIdx.x;
    int lane = tid & 63, wid = tid >> 6;
    int wr = wid >> 1, wc = wid & 1;          // 2x2 wave grid, each wave 64x64
    int bid = blockIdx.y * NX + blockIdx.x;
    bid = (bid & 7) * (NWG / 8) + (bid >> 3);   // bijective XCD swizzle
    int m0 = (bid / NX) * 128, n0 = (bid % NX) * 128;
    f32x4 acc[4][4];
#pragma unroll
    for (int i = 0; i < 4; i++)
#pragma unroll
        for (int j = 0; j < 4; j++) acc[i][j] = (f32x4){0.f, 0.f, 0.f, 0.f};

    int rl = lane & 15;
    int kb = (lane >> 4) * 8;

    for (int k0 = 0; k0 < K; k0 += 32) {
#pragma unroll
        for (int c = 0; c < 2; c++) {
            int s = c * 256 + tid;
            int r = s >> 2, sg = (s & 3) * 8;
            gload_lds16(A + (size_t)(m0 + r) * K + k0 + sg, &As[(c * 256 + wid * 64) * 8]);
            gload_lds16(Bt + (size_t)(n0 + r) * K + k0 + sg, &Bs[(c * 256 + wid * 64) * 8]);
        }
        __syncthreads();
        bf16x8 av[4], bv[4];
#pragma unroll
        for (int i = 0; i < 4; i++)
            av[i] = *(const bf16x8*)&As[(wr * 64 + i * 16 + rl) * 32 + kb];
#pragma unroll
        for (int j = 0; j < 4; j++)
            bv[j] = *(const bf16x8*)&Bs[(wc * 64 + j * 16 + rl) * 32 + kb];
#pragma unroll
        for (int i = 0; i < 4; i++)
#pragma unroll
            for (int j = 0; j < 4; j++)
                acc[i][j] = __builtin_amdgcn_mfma_f32_16x16x32_bf16(av[i], bv[j], acc[i][j], 0, 0, 0);
        __syncthreads();
    }
#pragma unroll
    for (int i = 0; i < 4; i++) {
        int mrow = m0 + wr * 64 + i * 16 + (lane >> 4) * 4;
#pragma unroll
        for (int j = 0; j < 4; j++) {
            int ncol = n0 + wc * 64 + j * 16 + rl;
#pragma unroll
            for (int r = 0; r < 4; r++) {
                float v = acc[i][j][r];
                int m = mrow + r;
                if (ncol < DI_) u_pre[(size_t)m * DI_ + ncol] = f2b(v);
                else            z_s[(size_t)m * DI_ + (ncol - DI_)] = f2b(silu_f(v));
            }
        }
    }
}

// ---------------- MFMA GEMM 2 (dbuf + T14 split): out = x + 0.5*(g_f+g_b) @ W_out ----------------
__global__ __launch_bounds__(256) void gemm_out_mfma(const bf16* __restrict__ gf,
                                                     const bf16* __restrict__ gb,
                                                     const bf16* __restrict__ Bt,   // [768][1536]
                                                     const float* __restrict__ resid,
                                                     float* __restrict__ C) {
    const int K = DI_, N = D_;
    constexpr int KT = DI_ / 32;                  // 48
    constexpr int NX = D_ / 128;                  // 6
    constexpr int NWG = NX * (ROWS_ / 128);       // 384
    __shared__ __align__(16) short As[2][128 * 32];
    __shared__ __align__(16) short Bs[2][128 * 32];
    int tid = threadIdx.x;
    int lane = tid & 63, wid = tid >> 6;
    int wr = wid >> 1, wc = wid & 1;
    int bid = blockIdx.y * NX + blockIdx.x;
    bid = (bid & 7) * (NWG / 8) + (bid >> 3);
    int m0 = (bid / NX) * 128, n0 = (bid % NX) * 128;
    f32x4 acc[4][4];
#pragma unroll
    for (int i = 0; i < 4; i++)
#pragma unroll
        for (int j = 0; j < 4; j++) acc[i][j] = (f32x4){0.f, 0.f, 0.f, 0.f};

    int rl = lane & 15;
    int kb = (lane >> 4) * 8;
    int sr = tid >> 2, sg = (tid & 3) * 8;

    auto conv_store = [&](int buf, ushort4 a0, ushort4 a1, ushort4 b0, ushort4 b1, int c) {
        bf16x8 st;
        st[0] = f2bbits(bfb(a0.x) + bfb(b0.x));
        st[1] = f2bbits(bfb(a0.y) + bfb(b0.y));
        st[2] = f2bbits(bfb(a0.z) + bfb(b0.z));
        st[3] = f2bbits(bfb(a0.w) + bfb(b0.w));
        st[4] = f2bbits(bfb(a1.x) + bfb(b1.x));
        st[5] = f2bbits(bfb(a1.y) + bfb(b1.y));
        st[6] = f2bbits(bfb(a1.z) + bfb(b1.z));
        st[7] = f2bbits(bfb(a1.w) + bfb(b1.w));
        *(bf16x8*)&As[buf][(c * 256 + tid) * 8] = st;
    };

    // prologue: stage K-tile 0 into buffer 0
    {
#pragma unroll
        for (int c = 0; c < 2; c++) {
            size_t off = (size_t)(m0 + c * 64 + sr) * K + 0 + sg;
            const unsigned short* pf = (const unsigned short*)(gf + off);
            const unsigned short* pb = (const unsigned short*)(gb + off);
            ushort4 a0 = *(const ushort4*)pf, a1 = *(const ushort4*)(pf + 4);
            ushort4 b0 = *(const ushort4*)pb, b1 = *(const ushort4*)(pb + 4);
            conv_store(0, a0, a1, b0, b1, c);
            gload_lds16(Bt + (size_t)(n0 + c * 64 + sr) * K + 0 + sg, &Bs[0][(c * 256 + wid * 64) * 8]);
        }
    }
    __syncthreads();

    for (int kt = 0; kt < KT; kt++) {
        int cur = kt & 1;
        ushort4 ra0[2], ra1[2], rb0[2], rb1[2];
        if (kt + 1 < KT) {
            int k1 = (kt + 1) * 32;
#pragma unroll
            for (int c = 0; c < 2; c++) {
                size_t off = (size_t)(m0 + c * 64 + sr) * K + k1 + sg;
                const unsigned short* pf = (const unsigned short*)(gf + off);
                const unsigned short* pb = (const unsigned short*)(gb + off);
                ra0[c] = *(const ushort4*)pf; ra1[c] = *(const ushort4*)(pf + 4);
                rb0[c] = *(const ushort4*)pb; rb1[c] = *(const ushort4*)(pb + 4);
                gload_lds16(Bt + (size_t)(n0 + c * 64 + sr) * K + k1 + sg, &Bs[cur ^ 1][(c * 256 + wid * 64) * 8]);
            }
        }
        bf16x8 av[4], bv[4];
#pragma unroll
        for (int i = 0; i < 4; i++)
            av[i] = *(const bf16x8*)&As[cur][(wr * 64 + i * 16 + rl) * 32 + kb];
#pragma unroll
        for (int j = 0; j < 4; j++)
            bv[j] = *(const bf16x8*)&Bs[cur][(wc * 64 + j * 16 + rl) * 32 + kb];
#pragma unroll
        for (int i = 0; i < 4; i++)
#pragma unroll
            for (int j = 0; j < 4; j++)
                acc[i][j] = __builtin_amdgcn_mfma_f32_16x16x32_bf16(av[i], bv[j], acc[i][j], 0, 0, 0);
        if (kt + 1 < KT) {
#pragma unroll
            for (int c = 0; c < 2; c++)
                conv_store(cur ^ 1, ra0[c], ra1[c], rb0[c], rb1[c], c);
        }
        __syncthreads();
    }
#pragma unroll
    for (int i = 0; i < 4; i++) {
        int mrow = m0 + wr * 64 + i * 16 + (lane >> 4) * 4;
#pragma unroll
        for (int j = 0; j < 4; j++) {
            int ncol = n0 + wc * 64 + j * 16 + rl;
#pragma unroll
            for (int r = 0; r < 4; r++) {
                size_t idx = (size_t)(mrow + r) * N + ncol;
                C[idx] = resid[idx] + 0.5f * acc[i][j][r];
            }
        }
    }
}

// ---------------- conv(4) + silu, both dirs, 8 channels/thread (bf16x8) ----------------
__global__ __launch_bounds__(256) void conv_kernel8(const bf16* __restrict__ up,
                                                    const float* __restrict__ cw,
                                                    const float* __restrict__ cb,
                                                    bf16* __restrict__ uf,
                                                    bf16* __restrict__ ub) {
    const int dpb = DI_ / 8;                       // 192 thread-groups per row
    int idx = blockIdx.x * 256 + threadIdx.x;      // over ROWS_*DI_/8
    int d8 = (idx % dpb) * 8;
    int bl = idx / dpb;
    int l = bl % L_, b = bl / L_;
    const bf16* base = up + (size_t)b * L_ * DI_ + d8;
    float um[7][8];
#pragma unroll
    for (int k = 0; k < 7; k++) {
        int ll = l - 3 + k;
        if (ll >= 0 && ll < L_) {
            bf16x8 v = *(const bf16x8*)(base + (size_t)ll * DI_);
#pragma unroll
            for (int e = 0; e < 8; e++) um[k][e] = bfb((unsigned short)v[e]);
        } else {
#pragma unroll
            for (int e = 0; e < 8; e++) um[k][e] = 0.f;
        }
    }
    bf16x8 of, ob;
#pragma unroll
    for (int e = 0; e < 8; e++) {
        float4 w = *(const float4*)(cw + (size_t)(d8 + e) * 4);
        float bias = cb[d8 + e];
        float cf  = bias + um[0][e] * w.x + um[1][e] * w.y + um[2][e] * w.z + um[3][e] * w.w;
        float cbw = bias + um[6][e] * w.x + um[5][e] * w.y + um[4][e] * w.z + um[3][e] * w.w;
        of[e] = f2bbits(silu_f(cf));
        ob[e] = f2bbits(silu_f(cbw));
    }
    size_t oidx = (size_t)bl * DI_ + d8;
    *(bf16x8*)(uf + oidx) = of;
    *(bf16x8*)(ub + oidx) = ob;
}

// ---------------- MFMA xdb (dbuf): u @ W_x -> BC cols fp32 + dt_raw bf16 padded ----------------
__global__ __launch_bounds__(256) void xdb_mfma(const bf16* __restrict__ uf,
                                                const bf16* __restrict__ ub,
                                                const bf16* __restrict__ Wxt,   // [80][1536]
                                                float* __restrict__ xf,
                                                float* __restrict__ xb,
                                                bf16* __restrict__ drf,         // [ROWS][64]
                                                bf16* __restrict__ drb) {
    const bf16* u = blockIdx.y ? ub : uf;
    float* xout = blockIdx.y ? xb : xf;
    bf16* dout = blockIdx.y ? drb : drf;
    int m0 = blockIdx.x * 64;
    constexpr int KT = DI_ / 64;                  // 24
    __shared__ __align__(16) short As[2][64 * 64];
    int tid = threadIdx.x;
    int lane = tid & 63, wid = tid >> 6;
    int rl = lane & 15, hi = lane >> 4;
    f32x4 acc[5];
#pragma unroll
    for (int j = 0; j < 5; j++) acc[j] = (f32x4){0.f, 0.f, 0.f, 0.f};

    int r_loc = wid * 16 + rl;
    int srow = tid >> 3, schunk = tid & 7;
    int scs = schunk ^ (srow & 7);                // pre-swizzled source chunk (row&7 == (32+row)&7)

    // prologue
#pragma unroll
    for (int t = 0; t < 2; t++)
        gload_lds16(u + (size_t)(m0 + t * 32 + srow) * DI_ + 0 + scs * 8,
                    &As[0][(t * 256 + wid * 64) * 8]);
    __syncthreads();

    for (int kt = 0; kt < KT; kt++) {
        int cur = kt & 1;
        if (kt + 1 < KT) {
            int k1 = (kt + 1) * 64;
#pragma unroll
            for (int t = 0; t < 2; t++)
                gload_lds16(u + (size_t)(m0 + t * 32 + srow) * DI_ + k1 + scs * 8,
                            &As[cur ^ 1][(t * 256 + wid * 64) * 8]);
        }
        int k0 = kt * 64;
        bf16x8 av[2];
#pragma unroll
        for (int kc = 0; kc < 2; kc++) {
            int c = kc * 4 + hi;
            av[kc] = *(const bf16x8*)&As[cur][r_loc * 64 + ((c ^ (r_loc & 7)) * 8)];
        }
#pragma unroll
        for (int j = 0; j < 5; j++)
#pragma unroll
            for (int kc = 0; kc < 2; kc++) {
                bf16x8 bv = *(const bf16x8*)(Wxt + (size_t)(j * 16 + rl) * DI_ + k0 + kc * 32 + hi * 8);
                acc[j] = __builtin_amdgcn_mfma_f32_16x16x32_bf16(av[kc], bv, acc[j], 0, 0, 0);
            }
        __syncthreads();
    }
#pragma unroll
    for (int j = 0; j < 5; j++) {
        int col = j * 16 + rl;
#pragma unroll
        for (int r = 0; r < 4; r++) {
            int m = m0 + wid * 16 + hi * 4 + r;
            float v = acc[j][r];
            if (col >= DTR_) xout[(size_t)m * 80 + col] = v;          // B,C cols for scan
            if (col < DTR_)      dout[(size_t)m * 64 + col] = f2b(v); // dt_raw
            else if (col < 64)   dout[(size_t)m * 64 + col] = f2b(0.f); // K-pad zeros
        }
    }
}

// ---------------- MFMA dt: softplus(dt_raw @ W_dt + b), M=8192 N=1536 K=64(pad) ----------------
__global__ __launch_bounds__(256) void gemm_dt_mfma(const bf16* __restrict__ drf,
                                                    const bf16* __restrict__ drb,
                                                    const bf16* __restrict__ Wdt_t, // [1536][64]
                                                    const float* __restrict__ bdt,
                                                    bf16* __restrict__ dtf,
                                                    bf16* __restrict__ dtb) {
    const bf16* A = blockIdx.z ? drb : drf;
    bf16* out = blockIdx.z ? dtb : dtf;
    int m0 = blockIdx.y * 64;
    int n0 = blockIdx.x * 256;
    __shared__ __align__(16) short As[64 * 64];
    int tid = threadIdx.x, lane = tid & 63, wid = tid >> 6;
    int rl = lane & 15, hi = lane >> 4;
#pragma unroll
    for (int t = 0; t < 2; t++) {
        int s = t * 256 + tid;
        int row = s >> 3, c = s & 7;
        gload_lds16(A + (size_t)(m0 + row) * 64 + (c ^ (row & 7)) * 8,
                    &As[(t * 256 + wid * 64) * 8]);
    }
    __syncthreads();
    int r_loc = wid * 16 + rl;
    bf16x8 av[2];
#pragma unroll
    for (int kc = 0; kc < 2; kc++) {
        int c = kc * 4 + hi;
        av[kc] = *(const bf16x8*)&As[r_loc * 64 + ((c ^ (r_loc & 7)) * 8)];
    }
    f32x4 acc[16];
#pragma unroll
    for (int j = 0; j < 16; j++) acc[j] = (f32x4){0.f, 0.f, 0.f, 0.f};
#pragma unroll
    for (int j = 0; j < 16; j++)
#pragma unroll
        for (int kc = 0; kc < 2; kc++) {
            bf16x8 bv = *(const bf16x8*)(Wdt_t + (size_t)(n0 + j * 16 + rl) * 64 + kc * 32 + hi * 8);
            acc[j] = __builtin_amdgcn_mfma_f32_16x16x32_bf16(av[kc], bv, acc[j], 0, 0, 0);
        }
#pragma unroll
    for (int j = 0; j < 16; j++) {
        int n = n0 + j * 16 + rl;
        float bb = bdt[n];
#pragma unroll
        for (int r = 0; r < 4; r++) {
            int m = m0 + wid * 16 + hi * 4 + r;
            out[(size_t)m * DI_ + n] = f2b(softplus_f(acc[j][r] + bb));
        }
    }
}

// ================= chunked parallel scan (packed fp32, incremental pointers) =================
__global__ __launch_bounds__(256) void scan_part1(const bf16* __restrict__ dtf,
                                                  const bf16* __restrict__ dtb,
                                                  const bf16* __restrict__ uff,
                                                  const bf16* __restrict__ ubb,
                                                  const float* __restrict__ xdbf,
                                                  const float* __restrict__ xdbb,
                                                  const float* __restrict__ A_log,
                                                  float* __restrict__ Pbuf,
                                                  float* __restrict__ Ebuf,
                                                  int NC, int CL) {
    int dir = blockIdx.z;
    int b = blockIdx.y / NC, c = blockIdx.y % NC;
    int d = blockIdx.x * 256 + threadIdx.x;
    size_t cbase = (size_t)b * L_ * DI_ + d;
    const bf16* dt = (dir ? dtb : dtf) + cbase;
    const bf16* uu = (dir ? ubb : uff) + cbase;
    const float* xdb = (dir ? xdbb : xdbf) + (size_t)b * L_ * 80;

    float a[DS_];
    int fast = 1;
#pragma unroll
    for (int s = 0; s < DS_; s++) {
        a[s] = -__expf(A_log[d * DS_ + s]);
        fast = fast && (fabsf(a[s] + (float)(s + 1)) < 1e-4f * (s + 1));
    }
    fast = __syncthreads_and(fast);

    int t0 = c * CL;
    int l0 = dir ? (L_ - 1 - t0) : t0;
    int sD = dir ? -DI_ : DI_;
    int s80 = dir ? -80 : 80;
    const bf16* pdt = dt + (size_t)l0 * DI_;
    const bf16* pu  = uu + (size_t)l0 * DI_;
    const float* pbr = xdb + (size_t)l0 * 80 + DTR_;

    size_t base = (((size_t)(dir * B_ + b) * NC + c) * DS_) * DI_ + d;

    if (fast) {
        f32x2 h2[8];
#pragma unroll
        for (int k = 0; k < 8; k++) h2[k] = (f32x2){0.f, 0.f};
        float sdt = 0.f;
        for (int it = 0; it < CL; ++it) {
            float dtv = b2f(*pdt);
            float uv  = b2f(*pu);
            float xu = dtv * uv;
            sdt += dtv;
            float r = __expf(-dtv);
            f32x2 pw[8]; pow_tree(r, pw);
            float4 b0 = *(const float4*)(pbr);
            float4 b1 = *(const float4*)(pbr + 4);
            float4 b2v = *(const float4*)(pbr + 8);
            float4 b3 = *(const float4*)(pbr + 12);
            f32x2 B2[8] = {{b0.x, b0.y}, {b0.z, b0.w}, {b1.x, b1.y}, {b1.z, b1.w},
                           {b2v.x, b2v.y}, {b2v.z, b2v.w}, {b3.x, b3.y}, {b3.z, b3.w}};
            f32x2 xu2 = {xu, xu};
#pragma unroll
            for (int k = 0; k < 8; k++) h2[k] = h2[k] * pw[k] + xu2 * B2[k];
            pdt += sD; pu += sD; pbr += s80;
        }
        float Rc = __expf(-sdt);
        f32x2 pwP[8]; pow_tree(Rc, pwP);
#pragma unroll
        for (int k = 0; k < 8; k++) {
            Pbuf[base + (size_t)(2 * k) * DI_]     = pwP[k].x;
            Pbuf[base + (size_t)(2 * k + 1) * DI_] = pwP[k].y;
            Ebuf[base + (size_t)(2 * k) * DI_]     = h2[k].x;
            Ebuf[base + (size_t)(2 * k + 1) * DI_] = h2[k].y;
        }
    } else {
        float h[DS_], P[DS_];
#pragma unroll
        for (int s = 0; s < DS_; s++) { h[s] = 0.f; P[s] = 1.f; }
        for (int it = 0; it < CL; ++it) {
            float dtv = b2f(*pdt);
            float uv = b2f(*pu);
            float xu = dtv * uv;
            float4 b0 = *(const float4*)(pbr);
            float4 b1 = *(const float4*)(pbr + 4);
            float4 b2v = *(const float4*)(pbr + 8);
            float4 b3 = *(const float4*)(pbr + 12);
            float Bv[16] = {b0.x, b0.y, b0.z, b0.w, b1.x, b1.y, b1.z, b1.w,
                            b2v.x, b2v.y, b2v.z, b2v.w, b3.x, b3.y, b3.z, b3.w};
#pragma unroll
            for (int s = 0; s < DS_; s++) {
                float dA = __expf(dtv * a[s]);
                h[s] = h[s] * dA + xu * Bv[s];
                P[s] *= dA;
            }
            pdt += sD; pu += sD; pbr += s80;
        }
#pragma unroll
        for (int s = 0; s < DS_; s++) {
            Pbuf[base + (size_t)s * DI_] = P[s];
            Ebuf[base + (size_t)s * DI_] = h[s];
        }
    }
}

__global__ __launch_bounds__(256) void scan_part2(const float* __restrict__ Pbuf,
                                                  float* __restrict__ Ebuf,
                                                  int NC) {
    int idx = blockIdx.x * 256 + threadIdx.x;   // over 2*B*DS*DI
    int d = idx % DI_;
    int rest = idx / DI_;
    int s = rest % DS_;
    int bb = rest / DS_;                        // dir*B + b
    size_t base = ((size_t)bb * NC * DS_ + s) * DI_ + d;
    float H = 0.f;
    for (int c = 0; c < NC; c++) {
        size_t aa = base + (size_t)c * DS_ * DI_;
        float P = Pbuf[aa], E = Ebuf[aa];
        Ebuf[aa] = H;
        H = P * H + E;
    }
}

__global__ __launch_bounds__(256) void scan_part3(const bf16* __restrict__ dtf,
                                                  const bf16* __restrict__ dtb,
                                                  const bf16* __restrict__ uff,
                                                  const bf16* __restrict__ ubb,
                                                  const float* __restrict__ xdbf,
                                                  const float* __restrict__ xdbb,
                                                  const bf16* __restrict__ z_s,
                                                  const float* __restrict__ A_log,
                                                  const float* __restrict__ Dp_,
                                                  const float* __restrict__ Ebuf,
                                                  bf16* __restrict__ gf,
                                                  bf16* __restrict__ gb,
                                                  int NC, int CL) {
    int dir = blockIdx.z;
    int b = blockIdx.y / NC, c = blockIdx.y % NC;
    int d = blockIdx.x * 256 + threadIdx.x;
    size_t cbase = (size_t)b * L_ * DI_ + d;
    const bf16* dt = (dir ? dtb : dtf) + cbase;
    const bf16* uu = (dir ? ubb : uff) + cbase;
    const float* xdb = (dir ? xdbb : xdbf) + (size_t)b * L_ * 80;
    const bf16* zp = z_s + cbase;
    bf16* g = (dir ? gb : gf) + cbase;

    float a[DS_];
    int fast = 1;
#pragma unroll
    for (int s = 0; s < DS_; s++) {
        a[s] = -__expf(A_log[d * DS_ + s]);
        fast = fast && (fabsf(a[s] + (float)(s + 1)) < 1e-4f * (s + 1));
    }
    fast = __syncthreads_and(fast);
    float Dp = Dp_[d];

    size_t base = (((size_t)(dir * B_ + b) * NC + c) * DS_) * DI_ + d;

    int t0 = c * CL;
    int l0 = dir ? (L_ - 1 - t0) : t0;
    int sD = dir ? -DI_ : DI_;
    int s80 = dir ? -80 : 80;
    const bf16* pdt = dt + (size_t)l0 * DI_;
    const bf16* pu  = uu + (size_t)l0 * DI_;
    const bf16* pz  = zp + (size_t)l0 * DI_;
    bf16* pg = g + (size_t)l0 * DI_;
    const float* pbr = xdb + (size_t)l0 * 80 + DTR_;

    if (fast) {
        f32x2 h2[8];
#pragma unroll
        for (int k = 0; k < 8; k++)
            h2[k] = (f32x2){Ebuf[base + (size_t)(2 * k) * DI_],
                            Ebuf[base + (size_t)(2 * k + 1) * DI_]};
        for (int it = 0; it < CL; ++it) {
            float dtv = b2f(*pdt);
            float uv  = b2f(*pu);
            float zv  = b2f(*pz);
            float xu = dtv * uv;
            float r = __expf(-dtv);
            f32x2 pw[8]; pow_tree(r, pw);
            float4 b0 = *(const float4*)(pbr);
            float4 b1 = *(const float4*)(pbr + 4);
            float4 b2v = *(const float4*)(pbr + 8);
            float4 b3 = *(const float4*)(pbr + 12);
            float4 c0 = *(const float4*)(pbr + 16);
            float4 c1 = *(const float4*)(pbr + 20);
            float4 c2v = *(const float4*)(pbr + 24);
            float4 c3 = *(const float4*)(pbr + 28);
            f32x2 B2[8] = {{b0.x, b0.y}, {b0.z, b0.w}, {b1.x, b1.y}, {b1.z, b1.w},
                           {b2v.x, b2v.y}, {b2v.z, b2v.w}, {b3.x, b3.y}, {b3.z, b3.w}};
            f32x2 C2[8] = {{c0.x, c0.y}, {c0.z, c0.w}, {c1.x, c1.y}, {c1.z, c1.w},
                           {c2v.x, c2v.y}, {c2v.z, c2v.w}, {c3.x, c3.y}, {c3.z, c3.w}};
            f32x2 xu2 = {xu, xu};
            f32x2 y2 = {0.f, 0.f};
#pragma unroll
            for (int k = 0; k < 8; k++) {
                h2[k] = h2[k] * pw[k] + xu2 * B2[k];
                y2 = y2 + h2[k] * C2[k];
            }
            float y = y2.x + y2.y;
            *pg = f2b((y + uv * Dp) * zv);
            pdt += sD; pu += sD; pz += sD; pg += sD; pbr += s80;
        }
    } else {
        float h[DS_];
#pragma unroll
        for (int s = 0; s < DS_; s++) h[s] = Ebuf[base + (size_t)s * DI_];
        for (int it = 0; it < CL; ++it) {
            float dtv = b2f(*pdt);
            float uv = b2f(*pu);
            float zv = b2f(*pz);
            float xu = dtv * uv;
            float4 b0 = *(const float4*)(pbr);
            float4 b1 = *(const float4*)(pbr + 4);
            float4 b2v = *(const float4*)(pbr + 8);
            float4 b3 = *(const float4*)(pbr + 12);
            float4 c0 = *(const float4*)(pbr + 16);
            float4 c1 = *(const float4*)(pbr + 20);
            float4 c2v = *(const float4*)(pbr + 24);
            float4 c3 = *(const float4*)(pbr + 28);
            float Bv[16] = {b0.x, b0.y, b0.z, b0.w, b1.x, b1.y, b1.z, b1.w,
                            b2v.x, b2v.y, b2v.z, b2v.w, b3.x, b3.y, b3.z, b3.w};
            float Cv[16] = {c0.x, c0.y, c0.z, c0.w, c1.x, c1.y, c1.z, c1.w,
                            c2v.x, c2v.y, c2v.z, c2v.w, c3.x, c3.y, c3.z, c3.w};
            float y = 0.f;
#pragma unroll
            for (int s = 0; s < DS_; s++) {
                float dA = __expf(dtv * a[s]);
                h[s] = h[s] * dA + xu * Bv[s];
                y += h[s] * Cv[s];
            }
            *pg = f2b((y + uv * Dp) * zv);
            pdt += sD; pu += sD; pz += sD; pg += sD; pbr += s80;
        }
    }
}

// ---------------- legacy single-pass scan (ws fallback) ----------------
__global__ __launch_bounds__(256) void scan_kernel(const bf16* __restrict__ dtf,
                                                   const bf16* __restrict__ dtb,
                                                   const bf16* __restrict__ uff,
                                                   const bf16* __restrict__ ubb,
                                                   const float* __restrict__ xdbf,
                                                   const float* __restrict__ xdbb,
                                                   const bf16* __restrict__ z_s,
                                                   const float* __restrict__ A_log,
                                                   const float* __restrict__ Dp_,
                                                   bf16* __restrict__ gf,
                                                   bf16* __restrict__ gb) {
    int dir = blockIdx.z;
    int b = blockIdx.y;
    int d = blockIdx.x * 256 + threadIdx.x;
    size_t cbase = (size_t)b * L_ * DI_ + d;
    const bf16* dt = (dir ? dtb : dtf) + cbase;
    const bf16* uu = (dir ? ubb : uff) + cbase;
    const float* xdb = (dir ? xdbb : xdbf) + (size_t)b * L_ * 80;
    const bf16* zp = z_s + cbase;
    bf16* g = (dir ? gb : gf) + cbase;
    float a[DS_];
#pragma unroll
    for (int s = 0; s < DS_; s++) a[s] = -__expf(A_log[d * DS_ + s]);
    float Dp = Dp_[d];
    float h[DS_];
#pragma unroll
    for (int s = 0; s < DS_; s++) h[s] = 0.f;
    for (int tt = 0; tt < L_; ++tt) {
        int l = dir ? (L_ - 1 - tt) : tt;
        size_t off = (size_t)l * DI_;
        float dtv = b2f(dt[off]);
        float uv = b2f(uu[off]);
        float zv = b2f(zp[off]);
        float xu = dtv * uv;
        const float* br = xdb + (size_t)l * 80 + DTR_;
        float y = 0.f;
#pragma unroll
        for (int s = 0; s < DS_; s++) {
            float dA = __expf(dtv * a[s]);
            h[s] = h[s] * dA + xu * br[s];
            y += h[s] * br[16 + s];
        }
        g[off] = f2b((y + uv * Dp) * zv);
    }
}

extern "C" void kernel_launch(void* const* d_in, const int* in_sizes, int n_in,
                              void* d_out, int out_size, void* d_ws, size_t ws_size,
                              hipStream_t stream) {
    const float* x      = (const float*)d_in[0];
    const float* ln_w   = (const float*)d_in[1];
    const float* ln_b   = (const float*)d_in[2];
    const float* W_in   = (const float*)d_in[3];
    const float* conv_w = (const float*)d_in[4];
    const float* conv_b = (const float*)d_in[5];
    const float* W_x    = (const float*)d_in[6];
    const float* W_dt   = (const float*)d_in[7];
    const float* b_dt   = (const float*)d_in[8];
    const float* A_log  = (const float*)d_in[9];
    const float* D_par  = (const float*)d_in[10];
    const float* W_out  = (const float*)d_in[11];
    float* out = (float*)d_out;

    const size_t NBbf = (size_t)ROWS_ * DI_ * sizeof(bf16);     // 25,165,824 B
    const size_t XDB4 = (size_t)ROWS_ * 80 * sizeof(float);     //  2,621,440 B
    const size_t WT1  = (size_t)D_ * 2 * DI_ * sizeof(bf16);    //  4,718,592 B
    const size_t WT2  = (size_t)DI_ * D_ * sizeof(bf16);        //  2,359,296 B
    const size_t WXT  = (size_t)80 * DI_ * sizeof(bf16);        //    245,760 B
    const size_t WDT  = (size_t)DI_ * 64 * sizeof(bf16);        //    196,608 B
    const size_t DR   = (size_t)ROWS_ * 64 * sizeof(bf16);      //  1,048,576 B
    const size_t BASE = 7 * NBbf + 2 * XDB4 + WT1 + WT2 + WXT + WDT + 2 * DR;
    if (ws_size < BASE) return;  // diagnostic: absmax-fail instead of GPU fault

    auto pe_bytes = [&](int NC) { return (size_t)2 * B_ * NC * DS_ * DI_ * sizeof(float); };
    int NC = 0;
    if (ws_size >= BASE + 2 * pe_bytes(64)) NC = 64;
    else if (ws_size >= BASE + 2 * pe_bytes(32)) NC = 32;
    else if (ws_size >= BASE + 2 * pe_bytes(16)) NC = 16;
    const int CL = NC ? L_ / NC : 0;

    char* p = (char*)d_ws;
    bf16* z_s   = (bf16*)p;  p += NBbf;
    bf16* u_f   = (bf16*)p;  p += NBbf;
    bf16* u_b   = (bf16*)p;  p += NBbf;
    bf16* slotA = (bf16*)p;  p += NBbf;   // u_pre [gemm_in..conv] / dt_f [gemm_dt..scan]
    bf16* dt_b  = (bf16*)p;  p += NBbf;
    char* slotB = p;         p += NBbf;   // xn bf16 [ln..gemm_in] / g_f bf16 [scan..gemm_out]
    bf16* g_b   = (bf16*)p;  p += NBbf;
    float* xdb_f = (float*)p; p += XDB4;
    float* xdb_b = (float*)p; p += XDB4;
    bf16* Wt_in  = (bf16*)p;  p += WT1;   // [3072][768]
    bf16* Wt_out = (bf16*)p;  p += WT2;   // [768][1536]
    bf16* Wxt    = (bf16*)p;  p += WXT;   // [80][1536]
    bf16* Wdt_t  = (bf16*)p;  p += WDT;   // [1536][64]
    bf16* dr_f   = (bf16*)p;  p += DR;    // [8192][64]
    bf16* dr_b   = (bf16*)p;  p += DR;
    float* Pbuf = (float*)p;  p += NC ? pe_bytes(NC) : 0;
    float* Ebuf = (float*)p;

    bf16* u_pre = slotA;
    bf16* dt_f  = slotA;
    bf16* xn    = (bf16*)slotB;
    bf16* g_f   = (bf16*)slotB;

    // 0. weight conversions (independent of LN)
    convert_wt<<<dim3((2 * DI_) / 32, D_ / 32), 256, 0, stream>>>(W_in, Wt_in, D_, 2 * DI_);
    convert_wt<<<dim3(D_ / 32, DI_ / 32), 256, 0, stream>>>(W_out, Wt_out, DI_, D_);
    convert_wxt<<<(80 * DI_) / 256, 256, 0, stream>>>(W_x, Wxt);
    convert_wdt<<<(DI_ * 64) / 256, 256, 0, stream>>>(W_dt, Wdt_t);
    // 1. layernorm -> bf16
    ln_kernel<<<ROWS_, 256, 0, stream>>>(x, ln_w, ln_b, xn);
    // 2. xz = xn @ W_in (MFMA, round-9 single-buffer); u half -> bf16, z half -> silu -> bf16
    gemm_in_mfma<<<dim3((2 * DI_) / 128, ROWS_ / 128), 256, 0, stream>>>(xn, Wt_in, u_pre, z_s);
    // 3. conv + silu, both dirs (8 ch/thread)
    conv_kernel8<<<(ROWS_ * DI_ / 8) / 256, 256, 0, stream>>>(u_pre, conv_w, conv_b, u_f, u_b);
    // 4. xdb = u @ W_x (MFMA dbuf), both dirs; BC cols fp32 + dt_raw bf16 padded
    xdb_mfma<<<dim3(ROWS_ / 64, 2), 256, 0, stream>>>(u_f, u_b, Wxt, xdb_f, xdb_b, dr_f, dr_b);
    // 5. dt = softplus(dt_raw @ W_dt + b_dt) (MFMA), both dirs
    gemm_dt_mfma<<<dim3(DI_ / 256, ROWS_ / 64, 2), 256, 0, stream>>>(dr_f, dr_b, Wdt_t, b_dt, dt_f, dt_b);
    // 6. SSM scan (NC=64 preferred for occupancy)
    if (NC) {
        scan_part1<<<dim3(DI_ / 256, B_ * NC, 2), 256, 0, stream>>>(
            dt_f, dt_b, u_f, u_b, xdb_f, xdb_b, A_log, Pbuf, Ebuf, NC, CL);
        scan_part2<<<(2 * B_ * DS_ * DI_) / 256, 256, 0, stream>>>(Pbuf, Ebuf, NC);
        scan_part3<<<dim3(DI_ / 256, B_ * NC, 2), 256, 0, stream>>>(
            dt_f, dt_b, u_f, u_b, xdb_f, xdb_b, z_s, A_log, D_par, Ebuf, g_f, g_b, NC, CL);
    } else {
        scan_kernel<<<dim3(DI_ / 256, B_, 2), 256, 0, stream>>>(
            dt_f, dt_b, u_f, u_b, xdb_f, xdb_b, z_s, A_log, D_par, g_f, g_b);
    }
    // 7. out = x + 0.5 * (g_f + g_b) @ W_out (MFMA dbuf, resid fused)
    gemm_out_mfma<<<dim3(D_ / 128, ROWS_ / 128), 256, 0, stream>>>(g_f, g_b, Wt_out, x, out);
}